// Round 7
// baseline (355.010 us; speedup 1.0000x reference)
//
#include <hip/hip_runtime.h>
#include <math.h>

typedef unsigned short u16;
typedef __bf16 bf16x8 __attribute__((ext_vector_type(8)));
typedef float f32x4 __attribute__((ext_vector_type(4)));
typedef short s16x8 __attribute__((ext_vector_type(8)));
typedef short s16x4 __attribute__((ext_vector_type(4)));

__device__ __forceinline__ float b2f(u16 u) {
    union { unsigned i; float f; } c; c.i = ((unsigned)u) << 16; return c.f;
}
__device__ __forceinline__ u16 f2b(float f) {
    union { float f; unsigned i; } c; c.f = f;
    return (u16)((c.i + 0x7fffu + ((c.i >> 16) & 1u)) >> 16);
}
__device__ __forceinline__ float gelu_f(float v) {
    return 0.5f * v * (1.0f + erff(v * 0.70710678118654752f));
}
__device__ __forceinline__ void async_cp16(const u16* g, u16* l) {
    __builtin_amdgcn_global_load_lds((const __attribute__((address_space(1))) void*)g,
                                     (__attribute__((address_space(3))) void*)l, 16, 0, 0);
}

// ---- pipelined fused GEMM for G1/G2 ------------------------------------
// 128 rows x 512 cols per block, 512 threads (8 waves, 2 row x 4 col groups;
// per-wave 64x128, acc = 128 f32 -> 2 waves/SIMD is the register cap).
// K-loop: BK=32, double-buffered (2x40KB LDS), 4 phases per K-tile:
//   {2 ds_read (+af in p0) | prefetch-issue} -> s_barrier -> lgkmcnt(0) ->
//   setprio(1) 8 MFMA setprio(0) -> [p3: vmcnt(0) own prefetch] -> s_barrier
// Counted-wait discipline: prefetch loads stay in flight across ~3 phases;
// never an early drain (the R2/R3 failure). Swizzle: R3-verified BK=32
// row-pair swizzle, slot s(r,c8) = (r>>1)*8 + (((r&1)*4 + c8 + (r>>1))&7).
// mode 1: f32 sigmoid out (gate). mode 2: LN -> bf16. mode 3: gelu(LN) -> bf16.
__global__ __launch_bounds__(512, 2)
void gemm_8ph(const u16* __restrict__ A0, const u16* __restrict__ A1,
              const u16* __restrict__ W0, const u16* __restrict__ W1,
              const float* __restrict__ B0, const float* __restrict__ B1,
              const float* __restrict__ LG0, const float* __restrict__ LB0,
              const float* __restrict__ LG1, const float* __restrict__ LB1,
              void* __restrict__ O0v, void* __restrict__ O1v,
              int lda, int K, int ldo0, int ldo1, int mode0, int mode1)
{
    __shared__ u16 smem[2 * 20480];   // 2 x 40 KB staging; epilogue reuses [0,33.3KB)

    const int half = blockIdx.x;
    const int by = blockIdx.y;
    const u16* A = (half ? A1 : A0) + (size_t)by * 128 * lda;
    const u16* W = half ? W1 : W0;
    const float* bias = half ? B1 : B0;
    const float* lng = half ? LG1 : LG0;
    const float* lnb = half ? LB1 : LB0;
    void* outv = half ? O1v : O0v;
    const int ldo = half ? ldo1 : ldo0;
    const int mode = half ? mode1 : mode0;

    const int tid = threadIdx.x;
    const int lane = tid & 63;
    const int wave = tid >> 6;        // 0..7
    const int wrow = wave >> 2;       // 0/1 -> 64-row group
    const int wcol = wave & 3;        // 0..3 -> 128-col group
    const int fc = lane & 15;
    const int quad = lane >> 4;

    // stage-side inverse swizzle: p -> hi=p>>3, t7=((p&7)-hi)&7, r=2hi+(t7>>2), c8=t7&3
    int sar, sac;                     // A tile 128x32: 512 chunks, 1/thread
    { const int hi = tid >> 3, t7 = ((tid & 7) - hi) & 7; sar = 2 * hi + (t7 >> 2); sac = t7 & 3; }
    int swr[4], swc[4];               // W tile 512x32: 2048 chunks, 4/thread
#pragma unroll
    for (int c = 0; c < 4; ++c) {
        const int p = tid + 512 * c;
        const int hi = p >> 3, t7 = ((p & 7) - hi) & 7;
        swr[c] = 2 * hi + (t7 >> 2); swc[c] = t7 & 3;
    }
    // K-invariant fragment offsets (u16 index); frag k-slice = quad*8 -> c8=quad
    int aoff[4];
#pragma unroll
    for (int i = 0; i < 4; ++i) {
        const int r = wrow * 64 + i * 16 + fc;
        const int s = ((r >> 1) << 3) + ((((r & 1) << 2) + quad + (r >> 1)) & 7);
        aoff[i] = s * 8;
    }
    int woff[8];
#pragma unroll
    for (int jj = 0; jj < 8; ++jj) {
        const int r = wcol * 128 + jj * 16 + fc;
        const int s = ((r >> 1) << 3) + ((((r & 1) << 2) + quad + (r >> 1)) & 7);
        woff[jj] = s * 8;
    }

    f32x4 acc[4][8];
#pragma unroll
    for (int i = 0; i < 4; ++i)
#pragma unroll
        for (int j = 0; j < 8; ++j)
            acc[i][j] = f32x4{0.f, 0.f, 0.f, 0.f};

    const int NT = K >> 5;
    // prologue: stage tile 0 into buf0
    async_cp16(A + (size_t)sar * lda + sac * 8, smem + tid * 8);
#pragma unroll
    for (int c = 0; c < 4; ++c)
        async_cp16(W + (size_t)swr[c] * K + swc[c] * 8, smem + 4096 + (tid + 512 * c) * 8);
    asm volatile("s_waitcnt vmcnt(0)" ::: "memory");
    __builtin_amdgcn_s_barrier();
    __builtin_amdgcn_sched_barrier(0);

    for (int t = 0; t < NT; ++t) {
        const int cur = t & 1;
        const u16* bA = smem + cur * 20480;
        const u16* bW = bA + 4096;
        u16* nbase = smem + (cur ^ 1) * 20480;
        const int nk = (t + 1) << 5;
        const bool pf = (t + 1 < NT);

        bf16x8 af[4];
#pragma unroll
        for (int i = 0; i < 4; ++i) af[i] = *(const bf16x8*)&bA[aoff[i]];

#pragma unroll
        for (int p = 0; p < 4; ++p) {
            bf16x8 wfa = *(const bf16x8*)&bW[woff[2 * p]];
            bf16x8 wfb = *(const bf16x8*)&bW[woff[2 * p + 1]];
            if (pf) {            // prefetch issue spread over phases 0-2
                if (p == 0) {
                    async_cp16(A + (size_t)sar * lda + nk + sac * 8, nbase + tid * 8);
                    async_cp16(W + (size_t)swr[0] * K + nk + swc[0] * 8,
                               nbase + 4096 + tid * 8);
                    async_cp16(W + (size_t)swr[1] * K + nk + swc[1] * 8,
                               nbase + 4096 + (tid + 512) * 8);
                } else if (p == 1) {
                    async_cp16(W + (size_t)swr[2] * K + nk + swc[2] * 8,
                               nbase + 4096 + (tid + 1024) * 8);
                } else if (p == 2) {
                    async_cp16(W + (size_t)swr[3] * K + nk + swc[3] * 8,
                               nbase + 4096 + (tid + 1536) * 8);
                }
            }
            __builtin_amdgcn_s_barrier();
            asm volatile("s_waitcnt lgkmcnt(0)" ::: "memory");
            __builtin_amdgcn_sched_barrier(0);
            __builtin_amdgcn_s_setprio(1);
#pragma unroll
            for (int i = 0; i < 4; ++i) {
                acc[i][2 * p] =
                    __builtin_amdgcn_mfma_f32_16x16x32_bf16(af[i], wfa, acc[i][2 * p], 0, 0, 0);
                acc[i][2 * p + 1] =
                    __builtin_amdgcn_mfma_f32_16x16x32_bf16(af[i], wfb, acc[i][2 * p + 1], 0, 0, 0);
            }
            __builtin_amdgcn_s_setprio(0);
            if (p == 3 && pf)    // own prefetch landed (issued >=1-3 phases ago)
                asm volatile("s_waitcnt vmcnt(0)" ::: "memory");
            __builtin_amdgcn_s_barrier();   // with p==3: all waves' prefetch visible
            __builtin_amdgcn_sched_barrier(0);
        }
    }

    // ---- epilogues (bit-identical numerics to the R5 paths) ----
    float bb[8];
#pragma unroll
    for (int jj = 0; jj < 8; ++jj)
        bb[jj] = bias[wcol * 128 + jj * 16 + fc];

    if (mode == 1) {
        // gate: sigmoid f32 via LDS, 8 passes of 16 rows (33 KB)
        float* sf = (float*)smem;
        for (int q = 0; q < 8; ++q) {
            if (wrow == (q >> 2)) {
                const int i = q & 3;
#pragma unroll
                for (int jj = 0; jj < 8; ++jj) {
                    const int col = wcol * 128 + jj * 16 + fc;
#pragma unroll
                    for (int r = 0; r < 4; ++r)
                        sf[(quad * 4 + r) * 516 + col] =
                            1.0f / (1.0f + expf(-(acc[i][jj][r] + bb[jj])));
                }
            }
            __syncthreads();
            // consecutive-lane f32x4: conflict-free, coalesced (fixes R6's 16-way)
            float* o = (float*)outv;
#pragma unroll
            for (int it = 0; it < 4; ++it) {
                const int rl = it * 4 + (tid >> 7);
                const int cidx = (tid & 127) * 4;
                const int grow = by * 128 + q * 16 + rl;
                *(f32x4*)&o[(size_t)grow * ldo + cidx] = *(const f32x4*)&sf[rl * 516 + cidx];
            }
            __syncthreads();
        }
    } else {
        // LN (mode 2) / gelu(LN) (mode 3): 4 passes of 32 rows (33.3 KB)
        float gv[8], bv8[8];
#pragma unroll
        for (int e = 0; e < 8; ++e) {
            gv[e] = lng[lane * 8 + e];
            bv8[e] = lnb[lane * 8 + e];
        }
        for (int q = 0; q < 4; ++q) {
            if (wrow == (q >> 1)) {
                const int i0 = 2 * (q & 1);
#pragma unroll
                for (int i2 = 0; i2 < 2; ++i2)
#pragma unroll
                for (int jj = 0; jj < 8; ++jj) {
                    const int col = wcol * 128 + jj * 16 + fc;
#pragma unroll
                    for (int r = 0; r < 4; ++r)
                        smem[(i2 * 16 + quad * 4 + r) * 520 + col] =
                            f2b(acc[i0 + i2][jj][r] + bb[jj]);
                }
            }
            __syncthreads();
            // 32 rows / 8 waves = 4 rows per wave
            for (int rr = 0; rr < 4; ++rr) {
                const int rl = wave * 4 + rr;
                const int grow = by * 128 + q * 32 + rl;
                float x[8], s = 0.f, ss = 0.f;
                s16x8 xv = *(const s16x8*)&smem[rl * 520 + lane * 8];
#pragma unroll
                for (int e = 0; e < 8; ++e) { x[e] = b2f((u16)xv[e]); s += x[e]; ss += x[e] * x[e]; }
#pragma unroll
                for (int m = 32; m >= 1; m >>= 1) { s += __shfl_xor(s, m, 64); ss += __shfl_xor(ss, m, 64); }
                const float mean = s * (1.f / 512.f);
                const float var = ss * (1.f / 512.f) - mean * mean;
                const float rs = rsqrtf(var + 1e-5f);
                s16x8 ov;
#pragma unroll
                for (int e = 0; e < 8; ++e) {
                    float y = (x[e] - mean) * rs * gv[e] + bv8[e];
                    if (mode == 3) y = gelu_f(y);
                    ov[e] = (short)f2b(y);
                }
                *(s16x8*)&((u16*)outv)[(size_t)grow * ldo + lane * 8] = ov;
            }
            __syncthreads();
        }
    }
}

// ---- R5-proven small-GEMM kernel (F1, F2, G3) ---------------------------
template<int SUBN, int IR>
__global__ __launch_bounds__(256, 2)
void gemm_bt(const u16* __restrict__ A0, const u16* __restrict__ A1,
             const u16* __restrict__ W0, const u16* __restrict__ W1,
             const float* __restrict__ B0, const float* __restrict__ B1,
             const float* __restrict__ LG0, const float* __restrict__ LB0,
             const float* __restrict__ LG1, const float* __restrict__ LB1,
             void* __restrict__ O0v, void* __restrict__ O1v,
             int lda, int K, int halfBlocks, int ldo0, int ldo1,
             int mode0, int mode1)
{
    constexpr int BM   = IR * 16;
    constexpr int NCOL = 256 * SUBN;
    constexpr int WCH  = 8 * SUBN;
    constexpr int EPIW = NCOL + 8;
    constexpr int STAGEU = (BM + NCOL) * 64;
    constexpr int EPIS = (IR == 4) ? 64 * EPIW : 0;
    __shared__ u16 sm[(STAGEU > EPIS) ? STAGEU : EPIS];
    u16* sA = sm;
    u16* sW = sm + BM * 64;

    const int bx = blockIdx.x, by = blockIdx.y;
    const int half = (bx >= halfBlocks) ? 1 : 0;
    const int bxl = bx - half * halfBlocks;
    const u16* A = (half ? A1 : A0) + (size_t)by * BM * lda;
    const u16* W = (half ? W1 : W0) + (size_t)bxl * NCOL * K;
    const float* bias = half ? B1 : B0;
    const float* lng = half ? LG1 : LG0;
    const float* lnb = half ? LB1 : LB0;
    void* outv = half ? O1v : O0v;
    const int ldo = half ? ldo1 : ldo0;
    const int mode = half ? mode1 : mode0;

    const int tid = threadIdx.x;
    const int lane = tid & 63;
    const int wave = tid >> 6;
    const int fc = lane & 15;
    const int quad = lane >> 4;

    int par[2], pac[2];
#pragma unroll
    for (int c = 0; c < 2; ++c) {
        const int p = tid + 256 * c;
        par[c] = p >> 3;
        pac[c] = ((p & 7) - (par[c] & 7)) & 7;
    }
    int pwr[WCH], pwc[WCH];
#pragma unroll
    for (int c = 0; c < WCH; ++c) {
        const int p = tid + 256 * c;
        pwr[c] = p >> 3;
        pwc[c] = ((p & 7) - (pwr[c] & 7)) & 7;
    }

    f32x4 acc[IR][4 * SUBN];
#pragma unroll
    for (int i = 0; i < IR; ++i)
#pragma unroll
        for (int j = 0; j < 4 * SUBN; ++j)
            acc[i][j] = f32x4{0.f, 0.f, 0.f, 0.f};

    for (int k0 = 0; k0 < K; k0 += 64) {
#pragma unroll
        for (int c = 0; c < 2; ++c) {
            const int p = tid + 256 * c;
            if (p < BM * 8)
                async_cp16(A + (size_t)par[c] * lda + k0 + pac[c] * 8, &sA[p * 8]);
        }
#pragma unroll
        for (int c = 0; c < WCH; ++c)
            async_cp16(W + (size_t)pwr[c] * K + k0 + pwc[c] * 8,
                       &sW[(tid + 256 * c) * 8]);
        __syncthreads();

#pragma unroll
        for (int kk = 0; kk < 2; ++kk) {
            bf16x8 af[IR];
#pragma unroll
            for (int i = 0; i < IR; ++i) {
                const int ar = i * 16 + fc;
                const int slot = ar * 8 + ((kk * 4 + quad + (ar & 7)) & 7);
                af[i] = *(const bf16x8*)&sA[slot * 8];
            }
#pragma unroll
            for (int sub = 0; sub < SUBN; ++sub) {
                bf16x8 wf[4];
#pragma unroll
                for (int j = 0; j < 4; ++j) {
                    const int wr = wave * 64 * SUBN + sub * 64 + j * 16 + fc;
                    const int slot = wr * 8 + ((kk * 4 + quad + (wr & 7)) & 7);
                    wf[j] = *(const bf16x8*)&sW[slot * 8];
                }
#pragma unroll
                for (int i = 0; i < IR; ++i)
#pragma unroll
                    for (int j = 0; j < 4; ++j)
                        acc[i][sub * 4 + j] =
                            __builtin_amdgcn_mfma_f32_16x16x32_bf16(af[i], wf[j], acc[i][sub * 4 + j], 0, 0, 0);
            }
        }
        __syncthreads();
    }

    const int colb = bxl * NCOL;

    if (mode <= 1) {
#pragma unroll
        for (int sub = 0; sub < SUBN; ++sub)
#pragma unroll
        for (int j = 0; j < 4; ++j) {
            const int colh = colb + wave * 64 * SUBN + sub * 64 + j * 16 + fc;
            const float bv = bias[colh];
#pragma unroll
            for (int i = 0; i < IR; ++i)
#pragma unroll
            for (int r = 0; r < 4; ++r) {
                const int row = by * BM + i * 16 + quad * 4 + r;
                const float v = acc[i][sub * 4 + j][r] + bv;
                if (mode == 1)
                    ((float*)outv)[(size_t)row * ldo + colh] = 1.0f / (1.0f + expf(-v));
                else
                    ((u16*)outv)[(size_t)row * ldo + colh] = f2b(v);
            }
        }
    } else if constexpr (IR == 4) {
        float bb[SUBN * 4];
#pragma unroll
        for (int sub = 0; sub < SUBN; ++sub)
#pragma unroll
        for (int j = 0; j < 4; ++j)
            bb[sub * 4 + j] = bias[colb + wave * 64 * SUBN + sub * 64 + j * 16 + fc];
#pragma unroll
        for (int sub = 0; sub < SUBN; ++sub)
#pragma unroll
        for (int j = 0; j < 4; ++j) {
            const int col = wave * 64 * SUBN + sub * 64 + j * 16 + fc;
#pragma unroll
            for (int i = 0; i < 4; ++i)
#pragma unroll
            for (int r = 0; r < 4; ++r)
                sm[(i * 16 + quad * 4 + r) * EPIW + col] =
                    f2b(acc[i][sub * 4 + j][r] + bb[sub * 4 + j]);
        }
        __syncthreads();

        constexpr int CE = NCOL / 64;
        constexpr float INV = 1.0f / (float)NCOL;
        float gv[CE], bvv[CE];
#pragma unroll
        for (int e = 0; e < CE; ++e) {
            gv[e] = lng[lane * CE + e];
            bvv[e] = lnb[lane * CE + e];
        }
        for (int rr = 0; rr < 16; ++rr) {
            const int rl = wave * 16 + rr;
            const int grow = by * 64 + rl;
            float x[CE], s = 0.f, ss = 0.f;
            if constexpr (CE == 8) {
                s16x8 xv = *(const s16x8*)&sm[rl * EPIW + lane * 8];
#pragma unroll
                for (int e = 0; e < 8; ++e) { x[e] = b2f((u16)xv[e]); s += x[e]; ss += x[e] * x[e]; }
            } else {
                s16x4 xv = *(const s16x4*)&sm[rl * EPIW + lane * 4];
#pragma unroll
                for (int e = 0; e < 4; ++e) { x[e] = b2f((u16)xv[e]); s += x[e]; ss += x[e] * x[e]; }
            }
#pragma unroll
            for (int m = 32; m >= 1; m >>= 1) { s += __shfl_xor(s, m, 64); ss += __shfl_xor(ss, m, 64); }
            const float mean = s * INV;
            const float var = ss * INV - mean * mean;
            const float rs = rsqrtf(var + 1e-5f);
            float y[CE];
#pragma unroll
            for (int e = 0; e < CE; ++e) {
                y[e] = (x[e] - mean) * rs * gv[e] + bvv[e];
                if (mode >= 3) y[e] = gelu_f(y[e]);
            }
            if (mode == 4) {
                float* o = (float*)outv;
#pragma unroll
                for (int e = 0; e < CE; ++e)
                    o[(size_t)grow * ldo + colb + lane * CE + e] = y[e];
                if (lane == 0) {
                    o[(size_t)16384 * 768 + grow] = 1.0f;
                    o[(size_t)16384 * 769 + grow] = 1.0f;
                }
            } else {
                u16* o = (u16*)outv;
                if constexpr (CE == 8) {
                    s16x8 ov;
#pragma unroll
                    for (int e = 0; e < 8; ++e) ov[e] = (short)f2b(y[e]);
                    *(s16x8*)&o[(size_t)grow * ldo + colb + lane * 8] = ov;
                } else {
                    s16x4 ov;
#pragma unroll
                    for (int e = 0; e < 4; ++e) ov[e] = (short)f2b(y[e]);
                    *(s16x4*)&o[(size_t)grow * ldo + colb + lane * 4] = ov;
                }
            }
        }
    }
}

// ---- prep ---------------------------------------------------------------

__device__ __forceinline__ void cvt_quads(const float* __restrict__ src,
                                          u16* __restrict__ dst, int bi, int tid)
{
#pragma unroll
    for (int c = 0; c < 2; ++c) {
        const int q = bi * 512 + tid + 256 * c;
        f32x4 v = *(const f32x4*)(src + (size_t)q * 4);
        s16x4 o;
        o[0] = (short)f2b(v[0]); o[1] = (short)f2b(v[1]);
        o[2] = (short)f2b(v[2]); o[3] = (short)f2b(v[3]);
        *(s16x4*)(dst + (size_t)q * 4) = o;
    }
}

__device__ void transpose_cvt64(const float* __restrict__ src, int C,
                                u16* __restrict__ dst, int R,
                                int tr, int tc, int tid, float* sm)
{
    const int lr = tid >> 4, lc4 = (tid & 15) * 4;
#pragma unroll
    for (int m = 0; m < 4; ++m) {
        const int i = lr + m * 16;
        f32x4 v = *(const f32x4*)&src[(size_t)(tr + i) * C + tc + lc4];
#pragma unroll
        for (int mm = 0; mm < 4; ++mm) sm[i * 65 + lc4 + mm] = v[mm];
    }
    __syncthreads();
#pragma unroll
    for (int m = 0; m < 4; ++m) {
        const int j = lr + m * 16;
        s16x4 o;
#pragma unroll
        for (int mm = 0; mm < 4; ++mm)
            o[mm] = (short)f2b(sm[(size_t)(lc4 + mm) * 65 + j]);
        *(s16x4*)&dst[(size_t)(tc + j) * R + tr + lc4] = o;
    }
}

__device__ void matvec_rows(const float* __restrict__ M, const float* __restrict__ v,
                            const float* __restrict__ add1, const float* __restrict__ add2,
                            float* __restrict__ out, int r0, int tid, float* sm)
{
    for (int i = tid; i < 512; i += 256) sm[i] = v[i];
    __syncthreads();
    const int row = r0 + (tid & 63), q = tid >> 6;
    float s = 0.f;
    for (int k = q * 128; k < q * 128 + 128; k += 4) {
        f32x4 m = *(const f32x4*)&M[(size_t)row * 512 + k];
        s += m[0] * sm[k] + m[1] * sm[k + 1] + m[2] * sm[k + 2] + m[3] * sm[k + 3];
    }
    sm[512 + tid] = s;
    __syncthreads();
    if (tid < 64)
        out[r0 + tid] = sm[512 + tid] + sm[512 + tid + 64] + sm[512 + tid + 128] +
                        sm[512 + tid + 192] + add1[r0 + tid] + add2[r0 + tid];
}

__global__ __launch_bounds__(256)
void prep_cvt(const float* __restrict__ text, const float* __restrict__ num,
              const float* __restrict__ tp_w, const float* __restrict__ np_w,
              const float* __restrict__ g_w, const float* __restrict__ m1_w,
              const float* __restrict__ m2_w,
              const float* __restrict__ a1_wv, const float* __restrict__ a2_wv,
              const float* __restrict__ a1_wo, const float* __restrict__ a2_wo,
              const float* __restrict__ a1_bv, const float* __restrict__ a1_bo,
              const float* __restrict__ a2_bv, const float* __restrict__ a2_bo,
              const float* __restrict__ tp_b, const float* __restrict__ np_b,
              u16* __restrict__ EMBc, u16* __restrict__ Wbig,
              u16* __restrict__ g_bf, u16* __restrict__ m1_bf, u16* __restrict__ m2_bf,
              u16* __restrict__ a1_wvT, u16* __restrict__ a2_wvT,
              u16* __restrict__ tp_wT, u16* __restrict__ np_wT,
              u16* __restrict__ a1_wo_bf, u16* __restrict__ a2_wo_bf,
              float* __restrict__ w1, float* __restrict__ w2,
              float* __restrict__ zb)
{
    __shared__ float smem[64 * 65];
    const int b = blockIdx.x, tid = threadIdx.x;
    if (b < 4096) {
#pragma unroll
        for (int c = 0; c < 2; ++c) {
            const int q = b * 512 + tid + 256 * c;
            const int e = q * 4, row = e >> 9, col = e & 511;
            const float* src = (col < 256) ? text + (size_t)row * 256 + col
                                           : num + (size_t)row * 256 + (col - 256);
            f32x4 v = *(const f32x4*)src;
            s16x4 o;
            o[0] = (short)f2b(v[0]); o[1] = (short)f2b(v[1]);
            o[2] = (short)f2b(v[2]); o[3] = (short)f2b(v[3]);
            *(s16x4*)(EMBc + e) = o;
        }
    } else if (b < 4352) { cvt_quads(g_w, g_bf, b - 4096, tid); }
    else if (b < 4608) { cvt_quads(m1_w, m1_bf, b - 4352, tid); }
    else if (b < 4672) { cvt_quads(m2_w, m2_bf, b - 4608, tid); }
    else if (b < 4736) {
#pragma unroll
        for (int c = 0; c < 2; ++c) {
            const int q = (b - 4672) * 512 + tid + 256 * c;
            const int e = q * 4, row = e >> 8, col = e & 255;
            f32x4 v = *(const f32x4*)(np_w + e);
            s16x4 o;
            o[0] = (short)f2b(v[0]); o[1] = (short)f2b(v[1]);
            o[2] = (short)f2b(v[2]); o[3] = (short)f2b(v[3]);
            *(s16x4*)(Wbig + (size_t)row * 512 + 256 + col) = o;
        }
    } else if (b < 4800) {
#pragma unroll
        for (int c = 0; c < 2; ++c) {
            const int q = (b - 4736) * 512 + tid + 256 * c;
            const int e = q * 4, row = e >> 8, col = e & 255;
            f32x4 v = *(const f32x4*)(tp_w + e);
            s16x4 o;
            o[0] = (short)f2b(v[0]); o[1] = (short)f2b(v[1]);
            o[2] = (short)f2b(v[2]); o[3] = (short)f2b(v[3]);
            *(s16x4*)(Wbig + (size_t)(512 + row) * 512 + col) = o;
        }
    } else if (b < 4864) {
        const int t = b - 4800;
        transpose_cvt64(a1_wv, 512, a1_wvT, 512, (t >> 3) * 64, (t & 7) * 64, tid, smem);
    } else if (b < 4928) {
        const int t = b - 4864;
        transpose_cvt64(a2_wv, 512, a2_wvT, 512, (t >> 3) * 64, (t & 7) * 64, tid, smem);
    } else if (b < 4960) {
        const int t = b - 4928;
        transpose_cvt64(tp_w, 256, tp_wT, 512, (t >> 2) * 64, (t & 3) * 64, tid, smem);
    } else if (b < 4992) {
        const int t = b - 4960;
        transpose_cvt64(np_w, 256, np_wT, 512, (t >> 2) * 64, (t & 3) * 64, tid, smem);
    } else if (b < 5120) { cvt_quads(a1_wo, a1_wo_bf, b - 4992, tid); }
    else if (b < 5248) { cvt_quads(a2_wo, a2_wo_bf, b - 5120, tid); }
    else if (b < 5256) {
        matvec_rows(a1_wo, a1_bv, a1_bo, np_b, w1, (b - 5248) * 64, tid, smem);
    } else if (b < 5264) {
        matvec_rows(a2_wo, a2_bv, a2_bo, tp_b, w2, (b - 5256) * 64, tid, smem);
    } else {
        *(f32x4*)&zb[tid * 4] = f32x4{0.f, 0.f, 0.f, 0.f};
    }
}

__global__ __launch_bounds__(256)
void prep_bias(const u16* __restrict__ M1, const u16* __restrict__ M2,
               const float* __restrict__ tp_b, const float* __restrict__ np_b,
               const float* __restrict__ w1, const float* __restrict__ w2,
               float* __restrict__ bbig)
{
    __shared__ float sm[768];
    const int b = blockIdx.x, tid = threadIdx.x;
    const int side = b >> 3, r0 = (b & 7) * 64;
    const u16* M = side ? M2 : M1;
    const float* v = side ? np_b : tp_b;
    const float* w = side ? w2 : w1;
    float* out = bbig + side * 512;
    for (int i = tid; i < 512; i += 256) sm[i] = v[i];
    __syncthreads();
    const int row = r0 + (tid & 63), q = tid >> 6;
    float s = 0.f;
    for (int k = q * 128; k < q * 128 + 128; k += 8) {
        s16x8 m = *(const s16x8*)&M[(size_t)row * 512 + k];
#pragma unroll
        for (int j = 0; j < 8; ++j) s += b2f((u16)m[j]) * sm[k + j];
    }
    sm[512 + tid] = s;
    __syncthreads();
    if (tid < 64)
        out[r0 + tid] = sm[512 + tid] + sm[512 + tid + 64] + sm[512 + tid + 128] +
                        sm[512 + tid + 192] + w[r0 + tid];
}

extern "C" void kernel_launch(void* const* d_in, const int* in_sizes, int n_in,
                              void* d_out, int out_size, void* d_ws, size_t ws_size,
                              hipStream_t stream)
{
    const float* text  = (const float*)d_in[0];
    const float* num   = (const float*)d_in[1];
    const float* tp_w  = (const float*)d_in[2];
    const float* tp_b  = (const float*)d_in[3];
    const float* np_w  = (const float*)d_in[4];
    const float* np_b  = (const float*)d_in[5];
    const float* a1_wv = (const float*)d_in[8];
    const float* a1_bv = (const float*)d_in[11];
    const float* a1_wo = (const float*)d_in[12];
    const float* a1_bo = (const float*)d_in[13];
    const float* a2_wv = (const float*)d_in[16];
    const float* a2_bv = (const float*)d_in[19];
    const float* a2_wo = (const float*)d_in[20];
    const float* a2_bo = (const float*)d_in[21];
    const float* n1_g  = (const float*)d_in[22];
    const float* n1_b  = (const float*)d_in[23];
    const float* n2_g  = (const float*)d_in[24];
    const float* n2_b  = (const float*)d_in[25];
    const float* g_w   = (const float*)d_in[26];
    const float* g_b   = (const float*)d_in[27];
    const float* m1_w  = (const float*)d_in[28];
    const float* m1_b  = (const float*)d_in[29];
    const float* ln1_g = (const float*)d_in[30];
    const float* ln1_b = (const float*)d_in[31];
    const float* m2_w  = (const float*)d_in[32];
    const float* m2_b  = (const float*)d_in[33];
    const float* ln2_g = (const float*)d_in[34];
    const float* ln2_b = (const float*)d_in[35];

    float* outp = (float*)d_out;
    char* ob = (char*)d_out;
    char* ws = (char*)d_ws;
    const size_t KB = 1024, MB = 1048576;

    // d_out scratch: [0,16MB) dead until G3; [16,48MB) dead until G2 (EMBc)
    u16* Wbig    = (u16*)(ob);                       // 1 MB   [1024x512]
    u16* g_bf    = (u16*)(ob + 1 * MB);              // 1 MB   [512x1024]
    u16* m1_bf   = (u16*)(ob + 2 * MB);              // 1 MB   [512x1024]
    u16* a1_wvT  = (u16*)(ob + 3 * MB + 256 * KB);   // 512 KB [512x512]
    u16* a2_wvT  = (u16*)(ob + 3 * MB + 768 * KB);   // 512 KB
    u16* tp_wT   = (u16*)(ob + 4 * MB + 256 * KB);   // 256 KB [256x512]
    u16* np_wT   = (u16*)(ob + 4 * MB + 512 * KB);   // 256 KB
    u16* a1_wo_bf= (u16*)(ob + 4 * MB + 768 * KB);   // 512 KB [512x512]
    u16* a2_wo_bf= (u16*)(ob + 5 * MB + 256 * KB);   // 512 KB
    u16* M1      = (u16*)(ob + 5 * MB + 768 * KB);   // 512 KB [512x512]
    u16* M2      = (u16*)(ob + 6 * MB + 256 * KB);   // 512 KB
    float* w1    = (float*)(ob + 6 * MB + 768 * KB); // 2 KB
    float* w2    = w1 + 512;                         // 2 KB
    float* bbig  = w1 + 1024;                        // 4 KB
    float* zb    = w1 + 2048;                        // 4 KB
    u16* EMBc    = (u16*)(ob + 16 * MB);             // 16 MB [16384x512]
    // ws: X live prep->G2; m2_bf live prep->G3; h live G2->G3.
    u16* X     = (u16*)ws;                           // 32 MB [16384x1024]
    u16* m2_bf = (u16*)(ws + 32 * MB);               // 256 KB [256x512]
    u16* h     = (u16*)(ws + 48 * MB);               // 16 MB [16384x512]

    dim3 blk(256);

    // P1: conversions, transposes, w1/w2, zbias
    prep_cvt<<<5265, blk, 0, stream>>>(text, num, tp_w, np_w, g_w, m1_w, m2_w,
        a1_wv, a2_wv, a1_wo, a2_wo, a1_bv, a1_bo, a2_bv, a2_bo, tp_b, np_b,
        EMBc, Wbig, g_bf, m1_bf, m2_bf, a1_wvT, a2_wvT, tp_wT, np_wT,
        a1_wo_bf, a2_wo_bf, w1, w2, zb);
    // F1: M1 = a1_wo@a1_wv ; M2 = a2_wo@a2_wv   (16-row tiles -> 128 blocks)
    gemm_bt<1, 1><<<dim3(4, 32), blk, 0, stream>>>(a1_wo_bf, a2_wo_bf, a1_wvT, a2_wvT,
        zb, zb, nullptr, nullptr, nullptr, nullptr,
        M1, M2, 512, 512, 2, 512, 512, 0, 0);
    // PB: bbig = [M1@tp_b + w1 | M2@np_b + w2]
    prep_bias<<<16, blk, 0, stream>>>(M1, M2, tp_b, np_b, w1, w2, bbig);
    // F2: Wbig[0:512,0:256] = M1@tp_w ; Wbig[512:,256:] = M2@np_w (64 blocks)
    gemm_bt<1, 1><<<dim3(2, 32), blk, 0, stream>>>(M1, M2, tp_wT, np_wT,
        zb, zb, nullptr, nullptr, nullptr, nullptr,
        Wbig, Wbig + (size_t)512 * 512 + 256, 512, 512, 1, 512, 512, 0, 0);
    // G1+L1: X = LN(EMBc @ Wbig.T + bbig), pipelined 128x512 blocks
    gemm_8ph<<<dim3(2, 128), dim3(512), 0, stream>>>(EMBc, EMBc,
        Wbig, Wbig + (size_t)512 * 512, bbig, bbig + 512,
        n1_g, n1_b, n2_g, n2_b,
        X, X + 512, 512, 512, 1024, 1024, 2, 2);
    // G2+L2: gate = sigmoid(comb@g_w.T+g_b) -> d_out f32 ; h = gelu(LN1(comb@m1_w.T+m1_b))
    gemm_8ph<<<dim3(2, 128), dim3(512), 0, stream>>>(X, X, g_bf, m1_bf, g_b, m1_b,
        nullptr, nullptr, ln1_g, ln1_b,
        outp + (size_t)16384 * 256, h, 1024, 1024, 512, 512, 1, 3);
    // G3+L3: fused = gelu(LN2(h @ m2_w.T + m2_b)) -> d_out f32; attn = 1.0
    gemm_bt<1, 4><<<dim3(1, 256), blk, 0, stream>>>(h, h, m2_bf, m2_bf, m2_b, m2_b,
        ln2_g, ln2_b, ln2_g, ln2_b,
        outp, outp, 512, 512, 1, 256, 256, 4, 4);
}

// Round 8
// 346.859 us; speedup vs baseline: 1.0235x; 1.0235x over previous
//
#include <hip/hip_runtime.h>
#include <math.h>

typedef unsigned short u16;
typedef __bf16 bf16x8 __attribute__((ext_vector_type(8)));
typedef float f32x4 __attribute__((ext_vector_type(4)));
typedef short s16x8 __attribute__((ext_vector_type(8)));
typedef short s16x4 __attribute__((ext_vector_type(4)));

__device__ __forceinline__ float b2f(u16 u) {
    union { unsigned i; float f; } c; c.i = ((unsigned)u) << 16; return c.f;
}
__device__ __forceinline__ u16 f2b(float f) {
    union { float f; unsigned i; } c; c.f = f;
    return (u16)((c.i + 0x7fffu + ((c.i >> 16) & 1u)) >> 16);
}
__device__ __forceinline__ float gelu_f(float v) {
    return 0.5f * v * (1.0f + erff(v * 0.70710678118654752f));
}
__device__ __forceinline__ void async_cp16(const u16* g, u16* l) {
    __builtin_amdgcn_global_load_lds((const __attribute__((address_space(1))) void*)g,
                                     (__attribute__((address_space(3))) void*)l, 16, 0, 0);
}

// C[m][colh] = sum_k A[m][k]*W[colh][k] + bias[colh]; A/W bf16, bias f32.
// Block = (IR*16) rows x (256*SUBN) cols; 4 waves side-by-side in cols.
// REGW=0 (F1/F2/G3): R5-proven BK=64 single-buffered LDS staging for A and W.
// REGW=1 (G1/G2): W loaded global->VGPR per wave (no cross-wave W reuse ->
//   LDS staging of W bought nothing but the barrier-coupled stream that
//   dominated G1/G2); A double-buffered in LDS at 8KB/buf, one
//   __syncthreads per K-step whose vmcnt drain lands on a prefetch issued
//   a full compute-phase earlier.
// mode 0: bf16 store. mode 1: f32 sigmoid (REGW: coalesced via LDS).
// mode 2: LN -> bf16. mode 3: gelu(LN) -> bf16. mode 4: gelu(LN) -> f32 + attn ones.
// LN modes require halfBlocks==1 and IR==4.
template<int SUBN, int IR, int REGW>
__global__ __launch_bounds__(256, 2)
void gemm_bt(const u16* __restrict__ A0, const u16* __restrict__ A1,
             const u16* __restrict__ W0, const u16* __restrict__ W1,
             const float* __restrict__ B0, const float* __restrict__ B1,
             const float* __restrict__ LG0, const float* __restrict__ LB0,
             const float* __restrict__ LG1, const float* __restrict__ LB1,
             void* __restrict__ O0v, void* __restrict__ O1v,
             int lda, int K, int halfBlocks, int ldo0, int ldo1,
             int mode0, int mode1)
{
    constexpr int BM   = IR * 16;
    constexpr int NCOL = 256 * SUBN;
    constexpr int WCH  = 8 * SUBN;
    constexpr int EPIW = NCOL + 8;
    constexpr int STAGEU = REGW ? 2 * BM * 64 : (BM + NCOL) * 64;
    constexpr int EPIS = (IR == 4) ? 64 * EPIW : 0;
    __shared__ u16 sm[(STAGEU > EPIS) ? STAGEU : EPIS];
    u16* sA = sm;
    u16* sW = sm + BM * 64;   // REGW=0 only

    const int bx = blockIdx.x, by = blockIdx.y;
    const int half = (bx >= halfBlocks) ? 1 : 0;
    const int bxl = bx - half * halfBlocks;
    const u16* A = (half ? A1 : A0) + (size_t)by * BM * lda;
    const u16* W = (half ? W1 : W0) + (size_t)bxl * NCOL * K;
    const float* bias = half ? B1 : B0;
    const float* lng = half ? LG1 : LG0;
    const float* lnb = half ? LB1 : LB0;
    void* outv = half ? O1v : O0v;
    const int ldo = half ? ldo1 : ldo0;
    const int mode = half ? mode1 : mode0;

    const int tid = threadIdx.x;
    const int lane = tid & 63;
    const int wave = tid >> 6;
    const int fc = lane & 15;
    const int quad = lane >> 4;

    // chunk slot p (16B) holds row r=p>>3, logical k8-chunk c8=((p&7)-(r&7))&7;
    // physical slot for (r,c8) is r*8 + ((c8 + r)&7) -> bank-spread frag reads.
    int par[2], pac[2];
#pragma unroll
    for (int c = 0; c < 2; ++c) {
        const int p = tid + 256 * c;
        par[c] = p >> 3;
        pac[c] = ((p & 7) - (par[c] & 7)) & 7;
    }

    f32x4 acc[IR][4 * SUBN];
#pragma unroll
    for (int i = 0; i < IR; ++i)
#pragma unroll
        for (int j = 0; j < 4 * SUBN; ++j)
            acc[i][j] = f32x4{0.f, 0.f, 0.f, 0.f};

    if constexpr (REGW) {
        // ---- A dbuf in LDS, W direct global->VGPR ----
        auto STAGE_A = [&](int buf, int k0) {
#pragma unroll
            for (int c = 0; c < 2; ++c) {
                const int p = tid + 256 * c;
                if (p < BM * 8)
                    async_cp16(A + (size_t)par[c] * lda + k0 + pac[c] * 8,
                               &sm[buf * (BM * 64) + p * 8]);
            }
        };
        STAGE_A(0, 0);
        __syncthreads();
        int buf = 0;
        const int NT = K >> 6;
        for (int t = 0; t < NT; ++t) {
            const int k0 = t << 6;
            if (t + 1 < NT) STAGE_A(buf ^ 1, (t + 1) << 6);   // hidden under compute
            const u16* sAb = sm + buf * (BM * 64);
#pragma unroll
            for (int kk = 0; kk < 2; ++kk) {
                bf16x8 af[IR];
#pragma unroll
                for (int i = 0; i < IR; ++i) {
                    const int ar = i * 16 + fc;
                    const int slot = ar * 8 + ((kk * 4 + quad + (ar & 7)) & 7);
                    af[i] = *(const bf16x8*)&sAb[slot * 8];
                }
#pragma unroll
                for (int sub = 0; sub < SUBN; ++sub) {
                    bf16x8 wf[4];
#pragma unroll
                    for (int j = 0; j < 4; ++j) {
                        const int wr = wave * 64 * SUBN + sub * 64 + j * 16 + fc;
                        wf[j] = *(const bf16x8*)(W + (size_t)wr * K + k0 + kk * 32 + quad * 8);
                    }
#pragma unroll
                    for (int i = 0; i < IR; ++i)
#pragma unroll
                        for (int j = 0; j < 4; ++j)
                            acc[i][sub * 4 + j] =
                                __builtin_amdgcn_mfma_f32_16x16x32_bf16(af[i], wf[j], acc[i][sub * 4 + j], 0, 0, 0);
                }
            }
            __syncthreads();   // drains A prefetch (in flight ~whole step); fences buf swap
            buf ^= 1;
        }
    } else {
        // ---- R5-proven single-buffered A+W LDS staging ----
        int pwr[WCH], pwc[WCH];
#pragma unroll
        for (int c = 0; c < WCH; ++c) {
            const int p = tid + 256 * c;
            pwr[c] = p >> 3;
            pwc[c] = ((p & 7) - (pwr[c] & 7)) & 7;
        }
        for (int k0 = 0; k0 < K; k0 += 64) {
#pragma unroll
            for (int c = 0; c < 2; ++c) {
                const int p = tid + 256 * c;
                if (p < BM * 8)
                    async_cp16(A + (size_t)par[c] * lda + k0 + pac[c] * 8, &sA[p * 8]);
            }
#pragma unroll
            for (int c = 0; c < WCH; ++c)
                async_cp16(W + (size_t)pwr[c] * K + k0 + pwc[c] * 8,
                           &sW[(tid + 256 * c) * 8]);
            __syncthreads();

#pragma unroll
            for (int kk = 0; kk < 2; ++kk) {
                bf16x8 af[IR];
#pragma unroll
                for (int i = 0; i < IR; ++i) {
                    const int ar = i * 16 + fc;
                    const int slot = ar * 8 + ((kk * 4 + quad + (ar & 7)) & 7);
                    af[i] = *(const bf16x8*)&sA[slot * 8];
                }
#pragma unroll
                for (int sub = 0; sub < SUBN; ++sub) {
                    bf16x8 wf[4];
#pragma unroll
                    for (int j = 0; j < 4; ++j) {
                        const int wr = wave * 64 * SUBN + sub * 64 + j * 16 + fc;
                        const int slot = wr * 8 + ((kk * 4 + quad + (wr & 7)) & 7);
                        wf[j] = *(const bf16x8*)&sW[slot * 8];
                    }
#pragma unroll
                    for (int i = 0; i < IR; ++i)
#pragma unroll
                        for (int j = 0; j < 4; ++j)
                            acc[i][sub * 4 + j] =
                                __builtin_amdgcn_mfma_f32_16x16x32_bf16(af[i], wf[j], acc[i][sub * 4 + j], 0, 0, 0);
                }
            }
            __syncthreads();
        }
    }

    const int colb = bxl * NCOL;

    if (mode <= 1) {
        if constexpr (REGW) {
            // gate (mode 1): sigmoid f32, coalesced via LDS (fixes ~1.5x write amp).
            // 4 passes of 16 rows; sf = 16 x 516 f32 = 33 KB (fits in sm).
            float* sf = (float*)sm;
            float bb2[SUBN * 4];
#pragma unroll
            for (int sub = 0; sub < SUBN; ++sub)
#pragma unroll
            for (int j = 0; j < 4; ++j)
                bb2[sub * 4 + j] = bias[colb + wave * 64 * SUBN + sub * 64 + j * 16 + fc];
#pragma unroll
            for (int q = 0; q < IR; ++q) {
#pragma unroll
                for (int sub = 0; sub < SUBN; ++sub)
#pragma unroll
                for (int j = 0; j < 4; ++j) {
                    const int col = wave * 64 * SUBN + sub * 64 + j * 16 + fc;
#pragma unroll
                    for (int r = 0; r < 4; ++r)
                        sf[(quad * 4 + r) * 516 + col] =
                            1.0f / (1.0f + expf(-(acc[q][sub * 4 + j][r] + bb2[sub * 4 + j])));
                }
                __syncthreads();
                float* o = (float*)outv;
#pragma unroll
                for (int it = 0; it < 8; ++it) {
                    const int rl = it * 2 + (tid >> 7);
                    const int cidx = (tid & 127) * 4;
                    const int grow = by * BM + q * 16 + rl;
                    *(f32x4*)&o[(size_t)grow * ldo + colb + cidx] =
                        *(const f32x4*)&sf[rl * 516 + cidx];
                }
                __syncthreads();
            }
        } else {
            // direct stores (mode 0 bf16, mode 1 sigmoid f32)
#pragma unroll
            for (int sub = 0; sub < SUBN; ++sub)
#pragma unroll
            for (int j = 0; j < 4; ++j) {
                const int colh = colb + wave * 64 * SUBN + sub * 64 + j * 16 + fc;
                const float bv = bias[colh];
#pragma unroll
                for (int i = 0; i < IR; ++i)
#pragma unroll
                for (int r = 0; r < 4; ++r) {
                    const int row = by * BM + i * 16 + quad * 4 + r;
                    const float v = acc[i][sub * 4 + j][r] + bv;
                    if (mode == 1)
                        ((float*)outv)[(size_t)row * ldo + colh] = 1.0f / (1.0f + expf(-v));
                    else
                        ((u16*)outv)[(size_t)row * ldo + colh] = f2b(v);
                }
            }
        }
    } else if constexpr (IR == 4) {
        // fused LN epilogue (bit-identical numerics; unchanged from R5)
        float bb[SUBN * 4];
#pragma unroll
        for (int sub = 0; sub < SUBN; ++sub)
#pragma unroll
        for (int j = 0; j < 4; ++j)
            bb[sub * 4 + j] = bias[colb + wave * 64 * SUBN + sub * 64 + j * 16 + fc];
#pragma unroll
        for (int sub = 0; sub < SUBN; ++sub)
#pragma unroll
        for (int j = 0; j < 4; ++j) {
            const int col = wave * 64 * SUBN + sub * 64 + j * 16 + fc;
#pragma unroll
            for (int i = 0; i < 4; ++i)
#pragma unroll
            for (int r = 0; r < 4; ++r)
                sm[(i * 16 + quad * 4 + r) * EPIW + col] =
                    f2b(acc[i][sub * 4 + j][r] + bb[sub * 4 + j]);
        }
        __syncthreads();

        constexpr int CE = NCOL / 64;
        constexpr float INV = 1.0f / (float)NCOL;
        float gv[CE], bvv[CE];
#pragma unroll
        for (int e = 0; e < CE; ++e) {
            gv[e] = lng[lane * CE + e];
            bvv[e] = lnb[lane * CE + e];
        }
        for (int rr = 0; rr < 16; ++rr) {
            const int rl = wave * 16 + rr;
            const int grow = by * 64 + rl;
            float x[CE], s = 0.f, ss = 0.f;
            if constexpr (CE == 8) {
                s16x8 xv = *(const s16x8*)&sm[rl * EPIW + lane * 8];
#pragma unroll
                for (int e = 0; e < 8; ++e) { x[e] = b2f((u16)xv[e]); s += x[e]; ss += x[e] * x[e]; }
            } else {
                s16x4 xv = *(const s16x4*)&sm[rl * EPIW + lane * 4];
#pragma unroll
                for (int e = 0; e < 4; ++e) { x[e] = b2f((u16)xv[e]); s += x[e]; ss += x[e] * x[e]; }
            }
#pragma unroll
            for (int m = 32; m >= 1; m >>= 1) { s += __shfl_xor(s, m, 64); ss += __shfl_xor(ss, m, 64); }
            const float mean = s * INV;
            const float var = ss * INV - mean * mean;
            const float rs = rsqrtf(var + 1e-5f);
            float y[CE];
#pragma unroll
            for (int e = 0; e < CE; ++e) {
                y[e] = (x[e] - mean) * rs * gv[e] + bvv[e];
                if (mode >= 3) y[e] = gelu_f(y[e]);
            }
            if (mode == 4) {
                float* o = (float*)outv;
#pragma unroll
                for (int e = 0; e < CE; ++e)
                    o[(size_t)grow * ldo + colb + lane * CE + e] = y[e];
                if (lane == 0) {
                    o[(size_t)16384 * 768 + grow] = 1.0f;
                    o[(size_t)16384 * 769 + grow] = 1.0f;
                }
            } else {
                u16* o = (u16*)outv;
                if constexpr (CE == 8) {
                    s16x8 ov;
#pragma unroll
                    for (int e = 0; e < 8; ++e) ov[e] = (short)f2b(y[e]);
                    *(s16x8*)&o[(size_t)grow * ldo + colb + lane * 8] = ov;
                } else {
                    s16x4 ov;
#pragma unroll
                    for (int e = 0; e < 4; ++e) ov[e] = (short)f2b(y[e]);
                    *(s16x4*)&o[(size_t)grow * ldo + colb + lane * 4] = ov;
                }
            }
        }
    }
}

// ---- prep ---------------------------------------------------------------

__device__ __forceinline__ void cvt_quads(const float* __restrict__ src,
                                          u16* __restrict__ dst, int bi, int tid)
{
#pragma unroll
    for (int c = 0; c < 2; ++c) {
        const int q = bi * 512 + tid + 256 * c;
        f32x4 v = *(const f32x4*)(src + (size_t)q * 4);
        s16x4 o;
        o[0] = (short)f2b(v[0]); o[1] = (short)f2b(v[1]);
        o[2] = (short)f2b(v[2]); o[3] = (short)f2b(v[3]);
        *(s16x4*)(dst + (size_t)q * 4) = o;
    }
}

__device__ void transpose_cvt64(const float* __restrict__ src, int C,
                                u16* __restrict__ dst, int R,
                                int tr, int tc, int tid, float* sm)
{
    const int lr = tid >> 4, lc4 = (tid & 15) * 4;
#pragma unroll
    for (int m = 0; m < 4; ++m) {
        const int i = lr + m * 16;
        f32x4 v = *(const f32x4*)&src[(size_t)(tr + i) * C + tc + lc4];
#pragma unroll
        for (int mm = 0; mm < 4; ++mm) sm[i * 65 + lc4 + mm] = v[mm];
    }
    __syncthreads();
#pragma unroll
    for (int m = 0; m < 4; ++m) {
        const int j = lr + m * 16;
        s16x4 o;
#pragma unroll
        for (int mm = 0; mm < 4; ++mm)
            o[mm] = (short)f2b(sm[(size_t)(lc4 + mm) * 65 + j]);
        *(s16x4*)&dst[(size_t)(tc + j) * R + tr + lc4] = o;
    }
}

__device__ void matvec_rows(const float* __restrict__ M, const float* __restrict__ v,
                            const float* __restrict__ add1, const float* __restrict__ add2,
                            float* __restrict__ out, int r0, int tid, float* sm)
{
    for (int i = tid; i < 512; i += 256) sm[i] = v[i];
    __syncthreads();
    const int row = r0 + (tid & 63), q = tid >> 6;
    float s = 0.f;
    for (int k = q * 128; k < q * 128 + 128; k += 4) {
        f32x4 m = *(const f32x4*)&M[(size_t)row * 512 + k];
        s += m[0] * sm[k] + m[1] * sm[k + 1] + m[2] * sm[k + 2] + m[3] * sm[k + 3];
    }
    sm[512 + tid] = s;
    __syncthreads();
    if (tid < 64)
        out[r0 + tid] = sm[512 + tid] + sm[512 + tid + 64] + sm[512 + tid + 128] +
                        sm[512 + tid + 192] + add1[r0 + tid] + add2[r0 + tid];
}

__global__ __launch_bounds__(256)
void prep_cvt(const float* __restrict__ text, const float* __restrict__ num,
              const float* __restrict__ tp_w, const float* __restrict__ np_w,
              const float* __restrict__ g_w, const float* __restrict__ m1_w,
              const float* __restrict__ m2_w,
              const float* __restrict__ a1_wv, const float* __restrict__ a2_wv,
              const float* __restrict__ a1_wo, const float* __restrict__ a2_wo,
              const float* __restrict__ a1_bv, const float* __restrict__ a1_bo,
              const float* __restrict__ a2_bv, const float* __restrict__ a2_bo,
              const float* __restrict__ tp_b, const float* __restrict__ np_b,
              u16* __restrict__ EMBc, u16* __restrict__ Wbig,
              u16* __restrict__ g_bf, u16* __restrict__ m1_bf, u16* __restrict__ m2_bf,
              u16* __restrict__ a1_wvT, u16* __restrict__ a2_wvT,
              u16* __restrict__ tp_wT, u16* __restrict__ np_wT,
              u16* __restrict__ a1_wo_bf, u16* __restrict__ a2_wo_bf,
              float* __restrict__ w1, float* __restrict__ w2,
              float* __restrict__ zb)
{
    __shared__ float smem[64 * 65];
    const int b = blockIdx.x, tid = threadIdx.x;
    if (b < 4096) {
#pragma unroll
        for (int c = 0; c < 2; ++c) {
            const int q = b * 512 + tid + 256 * c;
            const int e = q * 4, row = e >> 9, col = e & 511;
            const float* src = (col < 256) ? text + (size_t)row * 256 + col
                                           : num + (size_t)row * 256 + (col - 256);
            f32x4 v = *(const f32x4*)src;
            s16x4 o;
            o[0] = (short)f2b(v[0]); o[1] = (short)f2b(v[1]);
            o[2] = (short)f2b(v[2]); o[3] = (short)f2b(v[3]);
            *(s16x4*)(EMBc + e) = o;
        }
    } else if (b < 4352) { cvt_quads(g_w, g_bf, b - 4096, tid); }
    else if (b < 4608) { cvt_quads(m1_w, m1_bf, b - 4352, tid); }
    else if (b < 4672) { cvt_quads(m2_w, m2_bf, b - 4608, tid); }
    else if (b < 4736) {
#pragma unroll
        for (int c = 0; c < 2; ++c) {
            const int q = (b - 4672) * 512 + tid + 256 * c;
            const int e = q * 4, row = e >> 8, col = e & 255;
            f32x4 v = *(const f32x4*)(np_w + e);
            s16x4 o;
            o[0] = (short)f2b(v[0]); o[1] = (short)f2b(v[1]);
            o[2] = (short)f2b(v[2]); o[3] = (short)f2b(v[3]);
            *(s16x4*)(Wbig + (size_t)row * 512 + 256 + col) = o;
        }
    } else if (b < 4800) {
#pragma unroll
        for (int c = 0; c < 2; ++c) {
            const int q = (b - 4736) * 512 + tid + 256 * c;
            const int e = q * 4, row = e >> 8, col = e & 255;
            f32x4 v = *(const f32x4*)(tp_w + e);
            s16x4 o;
            o[0] = (short)f2b(v[0]); o[1] = (short)f2b(v[1]);
            o[2] = (short)f2b(v[2]); o[3] = (short)f2b(v[3]);
            *(s16x4*)(Wbig + (size_t)(512 + row) * 512 + col) = o;
        }
    } else if (b < 4864) {
        const int t = b - 4800;
        transpose_cvt64(a1_wv, 512, a1_wvT, 512, (t >> 3) * 64, (t & 7) * 64, tid, smem);
    } else if (b < 4928) {
        const int t = b - 4864;
        transpose_cvt64(a2_wv, 512, a2_wvT, 512, (t >> 3) * 64, (t & 7) * 64, tid, smem);
    } else if (b < 4960) {
        const int t = b - 4928;
        transpose_cvt64(tp_w, 256, tp_wT, 512, (t >> 2) * 64, (t & 3) * 64, tid, smem);
    } else if (b < 4992) {
        const int t = b - 4960;
        transpose_cvt64(np_w, 256, np_wT, 512, (t >> 2) * 64, (t & 3) * 64, tid, smem);
    } else if (b < 5120) { cvt_quads(a1_wo, a1_wo_bf, b - 4992, tid); }
    else if (b < 5248) { cvt_quads(a2_wo, a2_wo_bf, b - 5120, tid); }
    else if (b < 5256) {
        matvec_rows(a1_wo, a1_bv, a1_bo, np_b, w1, (b - 5248) * 64, tid, smem);
    } else if (b < 5264) {
        matvec_rows(a2_wo, a2_bv, a2_bo, tp_b, w2, (b - 5256) * 64, tid, smem);
    } else {
        *(f32x4*)&zb[tid * 4] = f32x4{0.f, 0.f, 0.f, 0.f};
    }
}

__global__ __launch_bounds__(256)
void prep_bias(const u16* __restrict__ M1, const u16* __restrict__ M2,
               const float* __restrict__ tp_b, const float* __restrict__ np_b,
               const float* __restrict__ w1, const float* __restrict__ w2,
               float* __restrict__ bbig)
{
    __shared__ float sm[768];
    const int b = blockIdx.x, tid = threadIdx.x;
    const int side = b >> 3, r0 = (b & 7) * 64;
    const u16* M = side ? M2 : M1;
    const float* v = side ? np_b : tp_b;
    const float* w = side ? w2 : w1;
    float* out = bbig + side * 512;
    for (int i = tid; i < 512; i += 256) sm[i] = v[i];
    __syncthreads();
    const int row = r0 + (tid & 63), q = tid >> 6;
    float s = 0.f;
    for (int k = q * 128; k < q * 128 + 128; k += 8) {
        s16x8 m = *(const s16x8*)&M[(size_t)row * 512 + k];
#pragma unroll
        for (int j = 0; j < 8; ++j) s += b2f((u16)m[j]) * sm[k + j];
    }
    sm[512 + tid] = s;
    __syncthreads();
    if (tid < 64)
        out[r0 + tid] = sm[512 + tid] + sm[512 + tid + 64] + sm[512 + tid + 128] +
                        sm[512 + tid + 192] + w[r0 + tid];
}

extern "C" void kernel_launch(void* const* d_in, const int* in_sizes, int n_in,
                              void* d_out, int out_size, void* d_ws, size_t ws_size,
                              hipStream_t stream)
{
    const float* text  = (const float*)d_in[0];
    const float* num   = (const float*)d_in[1];
    const float* tp_w  = (const float*)d_in[2];
    const float* tp_b  = (const float*)d_in[3];
    const float* np_w  = (const float*)d_in[4];
    const float* np_b  = (const float*)d_in[5];
    const float* a1_wv = (const float*)d_in[8];
    const float* a1_bv = (const float*)d_in[11];
    const float* a1_wo = (const float*)d_in[12];
    const float* a1_bo = (const float*)d_in[13];
    const float* a2_wv = (const float*)d_in[16];
    const float* a2_bv = (const float*)d_in[19];
    const float* a2_wo = (const float*)d_in[20];
    const float* a2_bo = (const float*)d_in[21];
    const float* n1_g  = (const float*)d_in[22];
    const float* n1_b  = (const float*)d_in[23];
    const float* n2_g  = (const float*)d_in[24];
    const float* n2_b  = (const float*)d_in[25];
    const float* g_w   = (const float*)d_in[26];
    const float* g_b   = (const float*)d_in[27];
    const float* m1_w  = (const float*)d_in[28];
    const float* m1_b  = (const float*)d_in[29];
    const float* ln1_g = (const float*)d_in[30];
    const float* ln1_b = (const float*)d_in[31];
    const float* m2_w  = (const float*)d_in[32];
    const float* m2_b  = (const float*)d_in[33];
    const float* ln2_g = (const float*)d_in[34];
    const float* ln2_b = (const float*)d_in[35];

    float* outp = (float*)d_out;
    char* ob = (char*)d_out;
    char* ws = (char*)d_ws;
    const size_t KB = 1024, MB = 1048576;

    // d_out scratch: [0,16MB) dead until G3; [16,48MB) dead until G2 (EMBc)
    u16* Wbig    = (u16*)(ob);                       // 1 MB   [1024x512]
    u16* g_bf    = (u16*)(ob + 1 * MB);              // 1 MB   [512x1024]
    u16* m1_bf   = (u16*)(ob + 2 * MB);              // 1 MB   [512x1024]
    u16* a1_wvT  = (u16*)(ob + 3 * MB + 256 * KB);   // 512 KB [512x512]
    u16* a2_wvT  = (u16*)(ob + 3 * MB + 768 * KB);   // 512 KB
    u16* tp_wT   = (u16*)(ob + 4 * MB + 256 * KB);   // 256 KB [256x512]
    u16* np_wT   = (u16*)(ob + 4 * MB + 512 * KB);   // 256 KB
    u16* a1_wo_bf= (u16*)(ob + 4 * MB + 768 * KB);   // 512 KB [512x512]
    u16* a2_wo_bf= (u16*)(ob + 5 * MB + 256 * KB);   // 512 KB
    u16* M1      = (u16*)(ob + 5 * MB + 768 * KB);   // 512 KB [512x512]
    u16* M2      = (u16*)(ob + 6 * MB + 256 * KB);   // 512 KB
    float* w1    = (float*)(ob + 6 * MB + 768 * KB); // 2 KB
    float* w2    = w1 + 512;                         // 2 KB
    float* bbig  = w1 + 1024;                        // 4 KB
    float* zb    = w1 + 2048;                        // 4 KB
    u16* EMBc    = (u16*)(ob + 16 * MB);             // 16 MB [16384x512]
    // ws: X live prep->G2; m2_bf live prep->G3; h live G2->G3.
    u16* X     = (u16*)ws;                           // 32 MB [16384x1024]
    u16* m2_bf = (u16*)(ws + 32 * MB);               // 256 KB [256x512]
    u16* h     = (u16*)(ws + 48 * MB);               // 16 MB [16384x512]

    dim3 blk(256);

    // P1: conversions, transposes, w1/w2, zbias
    prep_cvt<<<5265, blk, 0, stream>>>(text, num, tp_w, np_w, g_w, m1_w, m2_w,
        a1_wv, a2_wv, a1_wo, a2_wo, a1_bv, a1_bo, a2_bv, a2_bo, tp_b, np_b,
        EMBc, Wbig, g_bf, m1_bf, m2_bf, a1_wvT, a2_wvT, tp_wT, np_wT,
        a1_wo_bf, a2_wo_bf, w1, w2, zb);
    // F1: M1 = a1_wo@a1_wv ; M2 = a2_wo@a2_wv   (16-row tiles -> 128 blocks)
    gemm_bt<1, 1, 0><<<dim3(4, 32), blk, 0, stream>>>(a1_wo_bf, a2_wo_bf, a1_wvT, a2_wvT,
        zb, zb, nullptr, nullptr, nullptr, nullptr,
        M1, M2, 512, 512, 2, 512, 512, 0, 0);
    // PB: bbig = [M1@tp_b + w1 | M2@np_b + w2]
    prep_bias<<<16, blk, 0, stream>>>(M1, M2, tp_b, np_b, w1, w2, bbig);
    // F2: Wbig[0:512,0:256] = M1@tp_w ; Wbig[512:,256:] = M2@np_w (64 blocks)
    gemm_bt<1, 1, 0><<<dim3(2, 32), blk, 0, stream>>>(M1, M2, tp_wT, np_wT,
        zb, zb, nullptr, nullptr, nullptr, nullptr,
        Wbig, Wbig + (size_t)512 * 512 + 256, 512, 512, 1, 512, 512, 0, 0);
    // G1+L1: X = LN(EMBc @ Wbig.T + bbig), reg-W kernel
    gemm_bt<2, 4, 1><<<dim3(2, 256), blk, 0, stream>>>(EMBc, EMBc,
        Wbig, Wbig + (size_t)512 * 512, bbig, bbig + 512,
        n1_g, n1_b, n2_g, n2_b,
        X, X + 512, 512, 512, 1, 1024, 1024, 2, 2);
    // G2+L2: gate = sigmoid(comb@g_w.T+g_b) -> d_out f32 ; h = gelu(LN1(comb@m1_w.T+m1_b))
    gemm_bt<2, 4, 1><<<dim3(2, 256), blk, 0, stream>>>(X, X, g_bf, m1_bf, g_b, m1_b,
        nullptr, nullptr, ln1_g, ln1_b,
        outp + (size_t)16384 * 256, h, 1024, 1024, 1, 512, 512, 1, 3);
    // G3+L3: fused = gelu(LN2(h @ m2_w.T + m2_b)) -> d_out f32; attn = 1.0
    gemm_bt<1, 4, 0><<<dim3(1, 256), blk, 0, stream>>>(h, h, m2_bf, m2_bf, m2_b, m2_b,
        ln2_g, ln2_b, ln2_g, ln2_b,
        outp, outp, 512, 512, 1, 256, 256, 4, 4);
}

// Round 9
// 295.585 us; speedup vs baseline: 1.2010x; 1.1735x over previous
//
#include <hip/hip_runtime.h>
#include <math.h>

typedef unsigned short u16;
typedef __bf16 bf16x8 __attribute__((ext_vector_type(8)));
typedef float f32x4 __attribute__((ext_vector_type(4)));
typedef short s16x8 __attribute__((ext_vector_type(8)));
typedef short s16x4 __attribute__((ext_vector_type(4)));

__device__ __forceinline__ float b2f(u16 u) {
    union { unsigned i; float f; } c; c.i = ((unsigned)u) << 16; return c.f;
}
__device__ __forceinline__ u16 f2b(float f) {
    union { float f; unsigned i; } c; c.f = f;
    return (u16)((c.i + 0x7fffu + ((c.i >> 16) & 1u)) >> 16);
}
__device__ __forceinline__ float gelu_f(float v) {
    return 0.5f * v * (1.0f + erff(v * 0.70710678118654752f));
}
__device__ __forceinline__ void async_cp16(const u16* g, u16* l) {
    __builtin_amdgcn_global_load_lds((const __attribute__((address_space(1))) void*)g,
                                     (__attribute__((address_space(3))) void*)l, 16, 0, 0);
}

// C[m][colh] = sum_k A[m][k]*W[colh][k] + bias[colh]; A/W bf16, bias f32.
// Block = (IR*16) rows x (256*SUBN) cols; 4 waves side-by-side in cols.
// K-loop: BK=64, single-buffered, plain __syncthreads. This structure is the
// measured optimum across 8 structural variants (dbuf-drain, counted-vmcnt,
// TLP-tiles, 1-block/CU big-tile, 4-phase pipeline, reg-W all regressed).
// mode 0: bf16 store. mode 1: f32 sigmoid (IR==4/SUBN==2: coalesced via LDS).
// mode 2: LN -> bf16. mode 3: gelu(LN) -> bf16. mode 4: gelu(LN) -> f32 + attn ones.
// LN modes require halfBlocks==1 (block spans the whole LN group) and IR==4.
template<int SUBN, int IR>
__global__ __launch_bounds__(256, 2)
void gemm_bt(const u16* __restrict__ A0, const u16* __restrict__ A1,
             const u16* __restrict__ W0, const u16* __restrict__ W1,
             const float* __restrict__ B0, const float* __restrict__ B1,
             const float* __restrict__ LG0, const float* __restrict__ LB0,
             const float* __restrict__ LG1, const float* __restrict__ LB1,
             void* __restrict__ O0v, void* __restrict__ O1v,
             int lda, int K, int halfBlocks, int ldo0, int ldo1,
             int mode0, int mode1)
{
    constexpr int BM   = IR * 16;
    constexpr int NCOL = 256 * SUBN;
    constexpr int WCH  = 8 * SUBN;
    constexpr int EPIW = NCOL + 8;
    constexpr int STAGEU = (BM + NCOL) * 64;
    constexpr int EPIS = (IR == 4) ? 64 * EPIW : 0;
    __shared__ u16 sm[(STAGEU > EPIS) ? STAGEU : EPIS];
    u16* sA = sm;
    u16* sW = sm + BM * 64;

    const int bx = blockIdx.x, by = blockIdx.y;
    const int half = (bx >= halfBlocks) ? 1 : 0;
    const int bxl = bx - half * halfBlocks;
    const u16* A = (half ? A1 : A0) + (size_t)by * BM * lda;
    const u16* W = (half ? W1 : W0) + (size_t)bxl * NCOL * K;
    const float* bias = half ? B1 : B0;
    const float* lng = half ? LG1 : LG0;
    const float* lnb = half ? LB1 : LB0;
    void* outv = half ? O1v : O0v;
    const int ldo = half ? ldo1 : ldo0;
    const int mode = half ? mode1 : mode0;

    const int tid = threadIdx.x;
    const int lane = tid & 63;
    const int wave = tid >> 6;
    const int fc = lane & 15;
    const int quad = lane >> 4;

    // chunk slot p (16B) holds row r=p>>3, logical k8-chunk c8=((p&7)-(r&7))&7;
    // physical slot for (r,c8) is r*8 + ((c8 + r)&7) -> bank-spread frag reads.
    int par[2], pac[2];
#pragma unroll
    for (int c = 0; c < 2; ++c) {
        const int p = tid + 256 * c;
        par[c] = p >> 3;
        pac[c] = ((p & 7) - (par[c] & 7)) & 7;
    }
    int pwr[WCH], pwc[WCH];
#pragma unroll
    for (int c = 0; c < WCH; ++c) {
        const int p = tid + 256 * c;
        pwr[c] = p >> 3;
        pwc[c] = ((p & 7) - (pwr[c] & 7)) & 7;
    }

    f32x4 acc[IR][4 * SUBN];
#pragma unroll
    for (int i = 0; i < IR; ++i)
#pragma unroll
        for (int j = 0; j < 4 * SUBN; ++j)
            acc[i][j] = f32x4{0.f, 0.f, 0.f, 0.f};

    for (int k0 = 0; k0 < K; k0 += 64) {
#pragma unroll
        for (int c = 0; c < 2; ++c) {
            const int p = tid + 256 * c;
            if (p < BM * 8)
                async_cp16(A + (size_t)par[c] * lda + k0 + pac[c] * 8, &sA[p * 8]);
        }
#pragma unroll
        for (int c = 0; c < WCH; ++c)
            async_cp16(W + (size_t)pwr[c] * K + k0 + pwc[c] * 8,
                       &sW[(tid + 256 * c) * 8]);
        __syncthreads();

#pragma unroll
        for (int kk = 0; kk < 2; ++kk) {
            bf16x8 af[IR];
#pragma unroll
            for (int i = 0; i < IR; ++i) {
                const int ar = i * 16 + fc;
                const int slot = ar * 8 + ((kk * 4 + quad + (ar & 7)) & 7);
                af[i] = *(const bf16x8*)&sA[slot * 8];
            }
#pragma unroll
            for (int sub = 0; sub < SUBN; ++sub) {
                bf16x8 wf[4];
#pragma unroll
                for (int j = 0; j < 4; ++j) {
                    const int wr = wave * 64 * SUBN + sub * 64 + j * 16 + fc;
                    const int slot = wr * 8 + ((kk * 4 + quad + (wr & 7)) & 7);
                    wf[j] = *(const bf16x8*)&sW[slot * 8];
                }
#pragma unroll
                for (int i = 0; i < IR; ++i)
#pragma unroll
                    for (int j = 0; j < 4; ++j)
                        acc[i][sub * 4 + j] =
                            __builtin_amdgcn_mfma_f32_16x16x32_bf16(af[i], wf[j], acc[i][sub * 4 + j], 0, 0, 0);
            }
        }
        __syncthreads();
    }

    const int colb = bxl * NCOL;

    if constexpr (IR == 4) {
        if (mode == 1) {
            if constexpr (SUBN == 2) {
                // gate: sigmoid f32, coalesced via LDS (fixes measured 65->49MB
                // write amplification of the scalar 16-lane scatter store).
                // 2 passes of 32 rows; sf = 32 x 528 f32 = 67.5 KB <= 72 KB.
                // Stride 528: 528%32==16 -> quads hit disjoint bank halves (<=2-way).
                float* sf = (float*)sm;
                float bb2[8];
#pragma unroll
                for (int sub = 0; sub < 2; ++sub)
#pragma unroll
                for (int j = 0; j < 4; ++j)
                    bb2[sub * 4 + j] = bias[colb + wave * 128 + sub * 64 + j * 16 + fc];
#pragma unroll
                for (int p = 0; p < 2; ++p) {
#pragma unroll
                    for (int i2 = 0; i2 < 2; ++i2) {
                        const int i = 2 * p + i2;
#pragma unroll
                        for (int sub = 0; sub < 2; ++sub)
#pragma unroll
                        for (int j = 0; j < 4; ++j) {
                            const int col = wave * 128 + sub * 64 + j * 16 + fc;
#pragma unroll
                            for (int r = 0; r < 4; ++r)
                                sf[(i2 * 16 + quad * 4 + r) * 528 + col] =
                                    1.0f / (1.0f + expf(-(acc[i][sub * 4 + j][r] + bb2[sub * 4 + j])));
                        }
                    }
                    __syncthreads();
                    // 32 rows x 512 f32, consecutive-lane f32x4 (4KB/instr, coalesced)
                    float* o = (float*)outv;
#pragma unroll
                    for (int it = 0; it < 16; ++it) {
                        const int idx = it * 1024 + tid * 4;   // f32 units
                        const int row = idx >> 9, col = idx & 511;
                        const int grow = by * 64 + p * 32 + row;
                        *(f32x4*)&o[(size_t)grow * ldo + colb + col] =
                            *(const f32x4*)&sf[row * 528 + col];
                    }
                    __syncthreads();
                }
            }
        } else if (mode == 0) {
            // direct bf16 store
#pragma unroll
            for (int sub = 0; sub < SUBN; ++sub)
#pragma unroll
            for (int j = 0; j < 4; ++j) {
                const int colh = colb + wave * 64 * SUBN + sub * 64 + j * 16 + fc;
                const float bv = bias[colh];
#pragma unroll
                for (int i = 0; i < IR; ++i)
#pragma unroll
                for (int r = 0; r < 4; ++r) {
                    const int row = by * BM + i * 16 + quad * 4 + r;
                    ((u16*)outv)[(size_t)row * ldo + colh] = f2b(acc[i][sub * 4 + j][r] + bv);
                }
            }
        } else {
            // fused LN epilogue (bit-identical numerics; R5-proven)
            float bb[SUBN * 4];
#pragma unroll
            for (int sub = 0; sub < SUBN; ++sub)
#pragma unroll
            for (int j = 0; j < 4; ++j)
                bb[sub * 4 + j] = bias[colb + wave * 64 * SUBN + sub * 64 + j * 16 + fc];
#pragma unroll
            for (int sub = 0; sub < SUBN; ++sub)
#pragma unroll
            for (int j = 0; j < 4; ++j) {
                const int col = wave * 64 * SUBN + sub * 64 + j * 16 + fc;
#pragma unroll
                for (int i = 0; i < 4; ++i)
#pragma unroll
                for (int r = 0; r < 4; ++r)
                    sm[(i * 16 + quad * 4 + r) * EPIW + col] =
                        f2b(acc[i][sub * 4 + j][r] + bb[sub * 4 + j]);
            }
            __syncthreads();

            constexpr int CE = NCOL / 64;
            constexpr float INV = 1.0f / (float)NCOL;
            float gv[CE], bvv[CE];
#pragma unroll
            for (int e = 0; e < CE; ++e) {
                gv[e] = lng[lane * CE + e];
                bvv[e] = lnb[lane * CE + e];
            }
            for (int rr = 0; rr < 16; ++rr) {
                const int rl = wave * 16 + rr;
                const int grow = by * 64 + rl;
                float x[CE], s = 0.f, ss = 0.f;
                if constexpr (CE == 8) {
                    s16x8 xv = *(const s16x8*)&sm[rl * EPIW + lane * 8];
#pragma unroll
                    for (int e = 0; e < 8; ++e) { x[e] = b2f((u16)xv[e]); s += x[e]; ss += x[e] * x[e]; }
                } else {
                    s16x4 xv = *(const s16x4*)&sm[rl * EPIW + lane * 4];
#pragma unroll
                    for (int e = 0; e < 4; ++e) { x[e] = b2f((u16)xv[e]); s += x[e]; ss += x[e] * x[e]; }
                }
#pragma unroll
                for (int m = 32; m >= 1; m >>= 1) { s += __shfl_xor(s, m, 64); ss += __shfl_xor(ss, m, 64); }
                const float mean = s * INV;
                const float var = ss * INV - mean * mean;
                const float rs = rsqrtf(var + 1e-5f);
                float y[CE];
#pragma unroll
                for (int e = 0; e < CE; ++e) {
                    y[e] = (x[e] - mean) * rs * gv[e] + bvv[e];
                    if (mode >= 3) y[e] = gelu_f(y[e]);
                }
                if (mode == 4) {
                    float* o = (float*)outv;
#pragma unroll
                    for (int e = 0; e < CE; ++e)
                        o[(size_t)grow * ldo + colb + lane * CE + e] = y[e];
                    if (lane == 0) {
                        o[(size_t)16384 * 768 + grow] = 1.0f;
                        o[(size_t)16384 * 769 + grow] = 1.0f;
                    }
                } else {
                    u16* o = (u16*)outv;
                    if constexpr (CE == 8) {
                        s16x8 ov;
#pragma unroll
                        for (int e = 0; e < 8; ++e) ov[e] = (short)f2b(y[e]);
                        *(s16x8*)&o[(size_t)grow * ldo + colb + lane * 8] = ov;
                    } else {
                        s16x4 ov;
#pragma unroll
                        for (int e = 0; e < 4; ++e) ov[e] = (short)f2b(y[e]);
                        *(s16x4*)&o[(size_t)grow * ldo + colb + lane * 4] = ov;
                    }
                }
            }
        }
    } else {
        // IR==1 small GEMMs: direct stores (mode 0 bf16, mode 1 sigmoid f32)
#pragma unroll
        for (int sub = 0; sub < SUBN; ++sub)
#pragma unroll
        for (int j = 0; j < 4; ++j) {
            const int colh = colb + wave * 64 * SUBN + sub * 64 + j * 16 + fc;
            const float bv = bias[colh];
#pragma unroll
            for (int i = 0; i < IR; ++i)
#pragma unroll
            for (int r = 0; r < 4; ++r) {
                const int row = by * BM + i * 16 + quad * 4 + r;
                const float v = acc[i][sub * 4 + j][r] + bv;
                if (mode == 1)
                    ((float*)outv)[(size_t)row * ldo + colh] = 1.0f / (1.0f + expf(-v));
                else
                    ((u16*)outv)[(size_t)row * ldo + colh] = f2b(v);
            }
        }
    }
}

// ---- prep ---------------------------------------------------------------

__device__ __forceinline__ void cvt_quads(const float* __restrict__ src,
                                          u16* __restrict__ dst, int bi, int tid)
{
#pragma unroll
    for (int c = 0; c < 2; ++c) {
        const int q = bi * 512 + tid + 256 * c;
        f32x4 v = *(const f32x4*)(src + (size_t)q * 4);
        s16x4 o;
        o[0] = (short)f2b(v[0]); o[1] = (short)f2b(v[1]);
        o[2] = (short)f2b(v[2]); o[3] = (short)f2b(v[3]);
        *(s16x4*)(dst + (size_t)q * 4) = o;
    }
}

__device__ void transpose_cvt64(const float* __restrict__ src, int C,
                                u16* __restrict__ dst, int R,
                                int tr, int tc, int tid, float* sm)
{
    const int lr = tid >> 4, lc4 = (tid & 15) * 4;
#pragma unroll
    for (int m = 0; m < 4; ++m) {
        const int i = lr + m * 16;
        f32x4 v = *(const f32x4*)&src[(size_t)(tr + i) * C + tc + lc4];
#pragma unroll
        for (int mm = 0; mm < 4; ++mm) sm[i * 65 + lc4 + mm] = v[mm];
    }
    __syncthreads();
#pragma unroll
    for (int m = 0; m < 4; ++m) {
        const int j = lr + m * 16;
        s16x4 o;
#pragma unroll
        for (int mm = 0; mm < 4; ++mm)
            o[mm] = (short)f2b(sm[(size_t)(lc4 + mm) * 65 + j]);
        *(s16x4*)&dst[(size_t)(tc + j) * R + tr + lc4] = o;
    }
}

__device__ void matvec_rows(const float* __restrict__ M, const float* __restrict__ v,
                            const float* __restrict__ add1, const float* __restrict__ add2,
                            float* __restrict__ out, int r0, int tid, float* sm)
{
    for (int i = tid; i < 512; i += 256) sm[i] = v[i];
    __syncthreads();
    const int row = r0 + (tid & 63), q = tid >> 6;
    float s = 0.f;
    for (int k = q * 128; k < q * 128 + 128; k += 4) {
        f32x4 m = *(const f32x4*)&M[(size_t)row * 512 + k];
        s += m[0] * sm[k] + m[1] * sm[k + 1] + m[2] * sm[k + 2] + m[3] * sm[k + 3];
    }
    sm[512 + tid] = s;
    __syncthreads();
    if (tid < 64)
        out[r0 + tid] = sm[512 + tid] + sm[512 + tid + 64] + sm[512 + tid + 128] +
                        sm[512 + tid + 192] + add1[r0 + tid] + add2[r0 + tid];
}

__global__ __launch_bounds__(256)
void prep_cvt(const float* __restrict__ text, const float* __restrict__ num,
              const float* __restrict__ tp_w, const float* __restrict__ np_w,
              const float* __restrict__ g_w, const float* __restrict__ m1_w,
              const float* __restrict__ m2_w,
              const float* __restrict__ a1_wv, const float* __restrict__ a2_wv,
              const float* __restrict__ a1_wo, const float* __restrict__ a2_wo,
              const float* __restrict__ a1_bv, const float* __restrict__ a1_bo,
              const float* __restrict__ a2_bv, const float* __restrict__ a2_bo,
              const float* __restrict__ tp_b, const float* __restrict__ np_b,
              u16* __restrict__ EMBc, u16* __restrict__ Wbig,
              u16* __restrict__ g_bf, u16* __restrict__ m1_bf, u16* __restrict__ m2_bf,
              u16* __restrict__ a1_wvT, u16* __restrict__ a2_wvT,
              u16* __restrict__ tp_wT, u16* __restrict__ np_wT,
              u16* __restrict__ a1_wo_bf, u16* __restrict__ a2_wo_bf,
              float* __restrict__ w1, float* __restrict__ w2,
              float* __restrict__ zb)
{
    __shared__ float smem[64 * 65];
    const int b = blockIdx.x, tid = threadIdx.x;
    if (b < 4096) {
#pragma unroll
        for (int c = 0; c < 2; ++c) {
            const int q = b * 512 + tid + 256 * c;
            const int e = q * 4, row = e >> 9, col = e & 511;
            const float* src = (col < 256) ? text + (size_t)row * 256 + col
                                           : num + (size_t)row * 256 + (col - 256);
            f32x4 v = *(const f32x4*)src;
            s16x4 o;
            o[0] = (short)f2b(v[0]); o[1] = (short)f2b(v[1]);
            o[2] = (short)f2b(v[2]); o[3] = (short)f2b(v[3]);
            *(s16x4*)(EMBc + e) = o;
        }
    } else if (b < 4352) { cvt_quads(g_w, g_bf, b - 4096, tid); }
    else if (b < 4608) { cvt_quads(m1_w, m1_bf, b - 4352, tid); }
    else if (b < 4672) { cvt_quads(m2_w, m2_bf, b - 4608, tid); }
    else if (b < 4736) {
#pragma unroll
        for (int c = 0; c < 2; ++c) {
            const int q = (b - 4672) * 512 + tid + 256 * c;
            const int e = q * 4, row = e >> 8, col = e & 255;
            f32x4 v = *(const f32x4*)(np_w + e);
            s16x4 o;
            o[0] = (short)f2b(v[0]); o[1] = (short)f2b(v[1]);
            o[2] = (short)f2b(v[2]); o[3] = (short)f2b(v[3]);
            *(s16x4*)(Wbig + (size_t)row * 512 + 256 + col) = o;
        }
    } else if (b < 4800) {
#pragma unroll
        for (int c = 0; c < 2; ++c) {
            const int q = (b - 4736) * 512 + tid + 256 * c;
            const int e = q * 4, row = e >> 8, col = e & 255;
            f32x4 v = *(const f32x4*)(tp_w + e);
            s16x4 o;
            o[0] = (short)f2b(v[0]); o[1] = (short)f2b(v[1]);
            o[2] = (short)f2b(v[2]); o[3] = (short)f2b(v[3]);
            *(s16x4*)(Wbig + (size_t)(512 + row) * 512 + col) = o;
        }
    } else if (b < 4864) {
        const int t = b - 4800;
        transpose_cvt64(a1_wv, 512, a1_wvT, 512, (t >> 3) * 64, (t & 7) * 64, tid, smem);
    } else if (b < 4928) {
        const int t = b - 4864;
        transpose_cvt64(a2_wv, 512, a2_wvT, 512, (t >> 3) * 64, (t & 7) * 64, tid, smem);
    } else if (b < 4960) {
        const int t = b - 4928;
        transpose_cvt64(tp_w, 256, tp_wT, 512, (t >> 2) * 64, (t & 3) * 64, tid, smem);
    } else if (b < 4992) {
        const int t = b - 4960;
        transpose_cvt64(np_w, 256, np_wT, 512, (t >> 2) * 64, (t & 3) * 64, tid, smem);
    } else if (b < 5120) { cvt_quads(a1_wo, a1_wo_bf, b - 4992, tid); }
    else if (b < 5248) { cvt_quads(a2_wo, a2_wo_bf, b - 5120, tid); }
    else if (b < 5256) {
        matvec_rows(a1_wo, a1_bv, a1_bo, np_b, w1, (b - 5248) * 64, tid, smem);
    } else if (b < 5264) {
        matvec_rows(a2_wo, a2_bv, a2_bo, tp_b, w2, (b - 5256) * 64, tid, smem);
    } else {
        *(f32x4*)&zb[tid * 4] = f32x4{0.f, 0.f, 0.f, 0.f};
    }
}

__global__ __launch_bounds__(256)
void prep_bias(const u16* __restrict__ M1, const u16* __restrict__ M2,
               const float* __restrict__ tp_b, const float* __restrict__ np_b,
               const float* __restrict__ w1, const float* __restrict__ w2,
               float* __restrict__ bbig)
{
    __shared__ float sm[768];
    const int b = blockIdx.x, tid = threadIdx.x;
    const int side = b >> 3, r0 = (b & 7) * 64;
    const u16* M = side ? M2 : M1;
    const float* v = side ? np_b : tp_b;
    const float* w = side ? w2 : w1;
    float* out = bbig + side * 512;
    for (int i = tid; i < 512; i += 256) sm[i] = v[i];
    __syncthreads();
    const int row = r0 + (tid & 63), q = tid >> 6;
    float s = 0.f;
    for (int k = q * 128; k < q * 128 + 128; k += 8) {
        s16x8 m = *(const s16x8*)&M[(size_t)row * 512 + k];
#pragma unroll
        for (int j = 0; j < 8; ++j) s += b2f((u16)m[j]) * sm[k + j];
    }
    sm[512 + tid] = s;
    __syncthreads();
    if (tid < 64)
        out[r0 + tid] = sm[512 + tid] + sm[512 + tid + 64] + sm[512 + tid + 128] +
                        sm[512 + tid + 192] + w[r0 + tid];
}

extern "C" void kernel_launch(void* const* d_in, const int* in_sizes, int n_in,
                              void* d_out, int out_size, void* d_ws, size_t ws_size,
                              hipStream_t stream)
{
    const float* text  = (const float*)d_in[0];
    const float* num   = (const float*)d_in[1];
    const float* tp_w  = (const float*)d_in[2];
    const float* tp_b  = (const float*)d_in[3];
    const float* np_w  = (const float*)d_in[4];
    const float* np_b  = (const float*)d_in[5];
    const float* a1_wv = (const float*)d_in[8];
    const float* a1_bv = (const float*)d_in[11];
    const float* a1_wo = (const float*)d_in[12];
    const float* a1_bo = (const float*)d_in[13];
    const float* a2_wv = (const float*)d_in[16];
    const float* a2_bv = (const float*)d_in[19];
    const float* a2_wo = (const float*)d_in[20];
    const float* a2_bo = (const float*)d_in[21];
    const float* n1_g  = (const float*)d_in[22];
    const float* n1_b  = (const float*)d_in[23];
    const float* n2_g  = (const float*)d_in[24];
    const float* n2_b  = (const float*)d_in[25];
    const float* g_w   = (const float*)d_in[26];
    const float* g_b   = (const float*)d_in[27];
    const float* m1_w  = (const float*)d_in[28];
    const float* m1_b  = (const float*)d_in[29];
    const float* ln1_g = (const float*)d_in[30];
    const float* ln1_b = (const float*)d_in[31];
    const float* m2_w  = (const float*)d_in[32];
    const float* m2_b  = (const float*)d_in[33];
    const float* ln2_g = (const float*)d_in[34];
    const float* ln2_b = (const float*)d_in[35];

    float* outp = (float*)d_out;
    char* ob = (char*)d_out;
    char* ws = (char*)d_ws;
    const size_t KB = 1024, MB = 1048576;

    // d_out scratch: [0,16MB) dead until G3; [16,48MB) dead until G2 (EMBc)
    u16* Wbig    = (u16*)(ob);                       // 1 MB   [1024x512]
    u16* g_bf    = (u16*)(ob + 1 * MB);              // 1 MB   [512x1024]
    u16* m1_bf   = (u16*)(ob + 2 * MB);              // 1 MB   [512x1024]
    u16* a1_wvT  = (u16*)(ob + 3 * MB + 256 * KB);   // 512 KB [512x512]
    u16* a2_wvT  = (u16*)(ob + 3 * MB + 768 * KB);   // 512 KB
    u16* tp_wT   = (u16*)(ob + 4 * MB + 256 * KB);   // 256 KB [256x512]
    u16* np_wT   = (u16*)(ob + 4 * MB + 512 * KB);   // 256 KB
    u16* a1_wo_bf= (u16*)(ob + 4 * MB + 768 * KB);   // 512 KB [512x512]
    u16* a2_wo_bf= (u16*)(ob + 5 * MB + 256 * KB);   // 512 KB
    u16* M1      = (u16*)(ob + 5 * MB + 768 * KB);   // 512 KB [512x512]
    u16* M2      = (u16*)(ob + 6 * MB + 256 * KB);   // 512 KB
    float* w1    = (float*)(ob + 6 * MB + 768 * KB); // 2 KB
    float* w2    = w1 + 512;                         // 2 KB
    float* bbig  = w1 + 1024;                        // 4 KB
    float* zb    = w1 + 2048;                        // 4 KB
    u16* EMBc    = (u16*)(ob + 16 * MB);             // 16 MB [16384x512]
    // ws: X live prep->G2; m2_bf live prep->G3; h live G2->G3.
    u16* X     = (u16*)ws;                           // 32 MB [16384x1024]
    u16* m2_bf = (u16*)(ws + 32 * MB);               // 256 KB [256x512]
    u16* h     = (u16*)(ws + 48 * MB);               // 16 MB [16384x512]

    dim3 blk(256);

    // P1: conversions, transposes, w1/w2, zbias
    prep_cvt<<<5265, blk, 0, stream>>>(text, num, tp_w, np_w, g_w, m1_w, m2_w,
        a1_wv, a2_wv, a1_wo, a2_wo, a1_bv, a1_bo, a2_bv, a2_bo, tp_b, np_b,
        EMBc, Wbig, g_bf, m1_bf, m2_bf, a1_wvT, a2_wvT, tp_wT, np_wT,
        a1_wo_bf, a2_wo_bf, w1, w2, zb);
    // F1: M1 = a1_wo@a1_wv ; M2 = a2_wo@a2_wv   (16-row tiles -> 128 blocks)
    gemm_bt<1, 1><<<dim3(4, 32), blk, 0, stream>>>(a1_wo_bf, a2_wo_bf, a1_wvT, a2_wvT,
        zb, zb, nullptr, nullptr, nullptr, nullptr,
        M1, M2, 512, 512, 2, 512, 512, 0, 0);
    // PB: bbig = [M1@tp_b + w1 | M2@np_b + w2]
    prep_bias<<<16, blk, 0, stream>>>(M1, M2, tp_b, np_b, w1, w2, bbig);
    // F2: Wbig[0:512,0:256] = M1@tp_w ; Wbig[512:,256:] = M2@np_w (64 blocks)
    gemm_bt<1, 1><<<dim3(2, 32), blk, 0, stream>>>(M1, M2, tp_wT, np_wT,
        zb, zb, nullptr, nullptr, nullptr, nullptr,
        Wbig, Wbig + (size_t)512 * 512 + 256, 512, 512, 1, 512, 512, 0, 0);
    // G1+L1: X = LN(EMBc @ Wbig.T + bbig) per 512-col half (n1 | n2), fused
    gemm_bt<2, 4><<<dim3(2, 256), blk, 0, stream>>>(EMBc, EMBc,
        Wbig, Wbig + (size_t)512 * 512, bbig, bbig + 512,
        n1_g, n1_b, n2_g, n2_b,
        X, X + 512, 512, 512, 1, 1024, 1024, 2, 2);
    // G2+L2: gate = sigmoid(comb@g_w.T+g_b) -> d_out f32 (coalesced) ; h = gelu(LN1(...))
    gemm_bt<2, 4><<<dim3(2, 256), blk, 0, stream>>>(X, X, g_bf, m1_bf, g_b, m1_b,
        nullptr, nullptr, ln1_g, ln1_b,
        outp + (size_t)16384 * 256, h, 1024, 1024, 1, 512, 512, 1, 3);
    // G3+L3: fused = gelu(LN2(h @ m2_w.T + m2_b)) -> d_out f32; attn = 1.0
    gemm_bt<1, 4><<<dim3(1, 256), blk, 0, stream>>>(h, h, m2_bf, m2_bf, m2_b, m2_b,
        ln2_g, ln2_b, ln2_g, ln2_b,
        outp, outp, 512, 512, 1, 256, 256, 4, 4);
}

// Round 12
// 293.588 us; speedup vs baseline: 1.2092x; 1.0068x over previous
//
#include <hip/hip_runtime.h>
#include <math.h>

typedef unsigned short u16;
typedef __bf16 bf16x8 __attribute__((ext_vector_type(8)));
typedef float f32x4 __attribute__((ext_vector_type(4)));
typedef short s16x8 __attribute__((ext_vector_type(8)));
typedef short s16x4 __attribute__((ext_vector_type(4)));

__device__ __forceinline__ float b2f(u16 u) {
    union { unsigned i; float f; } c; c.i = ((unsigned)u) << 16; return c.f;
}
__device__ __forceinline__ u16 f2b(float f) {
    union { float f; unsigned i; } c; c.f = f;
    return (u16)((c.i + 0x7fffu + ((c.i >> 16) & 1u)) >> 16);
}
__device__ __forceinline__ float gelu_f(float v) {
    return 0.5f * v * (1.0f + erff(v * 0.70710678118654752f));
}
__device__ __forceinline__ void async_cp16(const u16* g, u16* l) {
    __builtin_amdgcn_global_load_lds((const __attribute__((address_space(1))) void*)g,
                                     (__attribute__((address_space(3))) void*)l, 16, 0, 0);
}

// C[m][colh] = sum_k A[m][k]*W[colh][k] + bias[colh]; A/W bf16, bias f32.
// Block = (IR*16) rows x (256*SUBN) cols; 4 waves side-by-side in cols.
// K-loop: BK=64, single-buffered, plain __syncthreads. This structure is the
// measured optimum across 8 structural variants (dbuf-drain, counted-vmcnt,
// TLP-tiles, 1-block/CU big-tile, 4-phase pipeline, reg-W all regressed).
// mode 0: bf16 store. mode 1: f32 sigmoid (IR==4/SUBN==2: coalesced via LDS).
// mode 2: LN -> bf16. mode 3: gelu(LN) -> bf16. mode 4: gelu(LN) -> f32 + attn ones.
// LN modes require halfBlocks==1 (block spans the whole LN group) and IR==4.
template<int SUBN, int IR>
__global__ __launch_bounds__(256, 2)
void gemm_bt(const u16* __restrict__ A0, const u16* __restrict__ A1,
             const u16* __restrict__ W0, const u16* __restrict__ W1,
             const float* __restrict__ B0, const float* __restrict__ B1,
             const float* __restrict__ LG0, const float* __restrict__ LB0,
             const float* __restrict__ LG1, const float* __restrict__ LB1,
             void* __restrict__ O0v, void* __restrict__ O1v,
             int lda, int K, int halfBlocks, int ldo0, int ldo1,
             int mode0, int mode1)
{
    constexpr int BM   = IR * 16;
    constexpr int NCOL = 256 * SUBN;
    constexpr int WCH  = 8 * SUBN;
    constexpr int EPIW = NCOL + 8;
    constexpr int STAGEU = (BM + NCOL) * 64;
    constexpr int EPIS = (IR == 4) ? 64 * EPIW : 0;
    __shared__ u16 sm[(STAGEU > EPIS) ? STAGEU : EPIS];
    u16* sA = sm;
    u16* sW = sm + BM * 64;

    const int bx = blockIdx.x, by = blockIdx.y;
    const int half = (bx >= halfBlocks) ? 1 : 0;
    const int bxl = bx - half * halfBlocks;
    const u16* A = (half ? A1 : A0) + (size_t)by * BM * lda;
    const u16* W = (half ? W1 : W0) + (size_t)bxl * NCOL * K;
    const float* bias = half ? B1 : B0;
    const float* lng = half ? LG1 : LG0;
    const float* lnb = half ? LB1 : LB0;
    void* outv = half ? O1v : O0v;
    const int ldo = half ? ldo1 : ldo0;
    const int mode = half ? mode1 : mode0;

    const int tid = threadIdx.x;
    const int lane = tid & 63;
    const int wave = tid >> 6;
    const int fc = lane & 15;
    const int quad = lane >> 4;

    // chunk slot p (16B) holds row r=p>>3, logical k8-chunk c8=((p&7)-(r&7))&7;
    // physical slot for (r,c8) is r*8 + ((c8 + r)&7) -> bank-spread frag reads.
    int par[2], pac[2];
#pragma unroll
    for (int c = 0; c < 2; ++c) {
        const int p = tid + 256 * c;
        par[c] = p >> 3;
        pac[c] = ((p & 7) - (par[c] & 7)) & 7;
    }
    int pwr[WCH], pwc[WCH];
#pragma unroll
    for (int c = 0; c < WCH; ++c) {
        const int p = tid + 256 * c;
        pwr[c] = p >> 3;
        pwc[c] = ((p & 7) - (pwr[c] & 7)) & 7;
    }

    f32x4 acc[IR][4 * SUBN];
#pragma unroll
    for (int i = 0; i < IR; ++i)
#pragma unroll
        for (int j = 0; j < 4 * SUBN; ++j)
            acc[i][j] = f32x4{0.f, 0.f, 0.f, 0.f};

    for (int k0 = 0; k0 < K; k0 += 64) {
#pragma unroll
        for (int c = 0; c < 2; ++c) {
            const int p = tid + 256 * c;
            if (p < BM * 8)
                async_cp16(A + (size_t)par[c] * lda + k0 + pac[c] * 8, &sA[p * 8]);
        }
#pragma unroll
        for (int c = 0; c < WCH; ++c)
            async_cp16(W + (size_t)pwr[c] * K + k0 + pwc[c] * 8,
                       &sW[(tid + 256 * c) * 8]);
        __syncthreads();

#pragma unroll
        for (int kk = 0; kk < 2; ++kk) {
            bf16x8 af[IR];
#pragma unroll
            for (int i = 0; i < IR; ++i) {
                const int ar = i * 16 + fc;
                const int slot = ar * 8 + ((kk * 4 + quad + (ar & 7)) & 7);
                af[i] = *(const bf16x8*)&sA[slot * 8];
            }
#pragma unroll
            for (int sub = 0; sub < SUBN; ++sub) {
                bf16x8 wf[4];
#pragma unroll
                for (int j = 0; j < 4; ++j) {
                    const int wr = wave * 64 * SUBN + sub * 64 + j * 16 + fc;
                    const int slot = wr * 8 + ((kk * 4 + quad + (wr & 7)) & 7);
                    wf[j] = *(const bf16x8*)&sW[slot * 8];
                }
#pragma unroll
                for (int i = 0; i < IR; ++i)
#pragma unroll
                    for (int j = 0; j < 4; ++j)
                        acc[i][sub * 4 + j] =
                            __builtin_amdgcn_mfma_f32_16x16x32_bf16(af[i], wf[j], acc[i][sub * 4 + j], 0, 0, 0);
            }
        }
        __syncthreads();
    }

    const int colb = bxl * NCOL;

    if constexpr (IR == 4) {
        if (mode == 1) {
            if constexpr (SUBN == 2) {
                // gate: sigmoid f32, coalesced via LDS (fixes measured 65->49MB
                // write amplification of the scalar 16-lane scatter store).
                // 2 passes of 32 rows; sf = 32 x 528 f32 = 67.5 KB <= 72 KB.
                float* sf = (float*)sm;
                float bb2[8];
#pragma unroll
                for (int sub = 0; sub < 2; ++sub)
#pragma unroll
                for (int j = 0; j < 4; ++j)
                    bb2[sub * 4 + j] = bias[colb + wave * 128 + sub * 64 + j * 16 + fc];
#pragma unroll
                for (int p = 0; p < 2; ++p) {
#pragma unroll
                    for (int i2 = 0; i2 < 2; ++i2) {
                        const int i = 2 * p + i2;
#pragma unroll
                        for (int sub = 0; sub < 2; ++sub)
#pragma unroll
                        for (int j = 0; j < 4; ++j) {
                            const int col = wave * 128 + sub * 64 + j * 16 + fc;
#pragma unroll
                            for (int r = 0; r < 4; ++r)
                                sf[(i2 * 16 + quad * 4 + r) * 528 + col] =
                                    1.0f / (1.0f + expf(-(acc[i][sub * 4 + j][r] + bb2[sub * 4 + j])));
                        }
                    }
                    __syncthreads();
                    // 32 rows x 512 f32, consecutive-lane f32x4 (4KB/instr, coalesced)
                    float* o = (float*)outv;
#pragma unroll
                    for (int it = 0; it < 16; ++it) {
                        const int idx = it * 1024 + tid * 4;   // f32 units
                        const int row = idx >> 9, col = idx & 511;
                        const int grow = by * 64 + p * 32 + row;
                        *(f32x4*)&o[(size_t)grow * ldo + colb + col] =
                            *(const f32x4*)&sf[row * 528 + col];
                    }
                    __syncthreads();
                }
            }
        } else if (mode == 0) {
            // direct bf16 store
#pragma unroll
            for (int sub = 0; sub < SUBN; ++sub)
#pragma unroll
            for (int j = 0; j < 4; ++j) {
                const int colh = colb + wave * 64 * SUBN + sub * 64 + j * 16 + fc;
                const float bv = bias[colh];
#pragma unroll
                for (int i = 0; i < IR; ++i)
#pragma unroll
                for (int r = 0; r < 4; ++r) {
                    const int row = by * BM + i * 16 + quad * 4 + r;
                    ((u16*)outv)[(size_t)row * ldo + colh] = f2b(acc[i][sub * 4 + j][r] + bv);
                }
            }
        } else {
            // fused LN epilogue (bit-identical numerics; R5-proven)
            float bb[SUBN * 4];
#pragma unroll
            for (int sub = 0; sub < SUBN; ++sub)
#pragma unroll
            for (int j = 0; j < 4; ++j)
                bb[sub * 4 + j] = bias[colb + wave * 64 * SUBN + sub * 64 + j * 16 + fc];
#pragma unroll
            for (int sub = 0; sub < SUBN; ++sub)
#pragma unroll
            for (int j = 0; j < 4; ++j) {
                const int col = wave * 64 * SUBN + sub * 64 + j * 16 + fc;
#pragma unroll
                for (int i = 0; i < 4; ++i)
#pragma unroll
                for (int r = 0; r < 4; ++r)
                    sm[(i * 16 + quad * 4 + r) * EPIW + col] =
                        f2b(acc[i][sub * 4 + j][r] + bb[sub * 4 + j]);
            }
            __syncthreads();

            constexpr int CE = NCOL / 64;
            constexpr float INV = 1.0f / (float)NCOL;
            float gv[CE], bvv[CE];
#pragma unroll
            for (int e = 0; e < CE; ++e) {
                gv[e] = lng[lane * CE + e];
                bvv[e] = lnb[lane * CE + e];
            }
            for (int rr = 0; rr < 16; ++rr) {
                const int rl = wave * 16 + rr;
                const int grow = by * 64 + rl;
                float x[CE], s = 0.f, ss = 0.f;
                if constexpr (CE == 8) {
                    s16x8 xv = *(const s16x8*)&sm[rl * EPIW + lane * 8];
#pragma unroll
                    for (int e = 0; e < 8; ++e) { x[e] = b2f((u16)xv[e]); s += x[e]; ss += x[e] * x[e]; }
                } else {
                    s16x4 xv = *(const s16x4*)&sm[rl * EPIW + lane * 4];
#pragma unroll
                    for (int e = 0; e < 4; ++e) { x[e] = b2f((u16)xv[e]); s += x[e]; ss += x[e] * x[e]; }
                }
#pragma unroll
                for (int m = 32; m >= 1; m >>= 1) { s += __shfl_xor(s, m, 64); ss += __shfl_xor(ss, m, 64); }
                const float mean = s * INV;
                const float var = ss * INV - mean * mean;
                const float rs = rsqrtf(var + 1e-5f);
                float y[CE];
#pragma unroll
                for (int e = 0; e < CE; ++e) {
                    y[e] = (x[e] - mean) * rs * gv[e] + bvv[e];
                    if (mode >= 3) y[e] = gelu_f(y[e]);
                }
                if (mode == 4) {
                    float* o = (float*)outv;
#pragma unroll
                    for (int e = 0; e < CE; ++e)
                        o[(size_t)grow * ldo + colb + lane * CE + e] = y[e];
                    if (lane == 0) {
                        o[(size_t)16384 * 768 + grow] = 1.0f;
                        o[(size_t)16384 * 769 + grow] = 1.0f;
                    }
                } else {
                    u16* o = (u16*)outv;
                    if constexpr (CE == 8) {
                        s16x8 ov;
#pragma unroll
                        for (int e = 0; e < 8; ++e) ov[e] = (short)f2b(y[e]);
                        *(s16x8*)&o[(size_t)grow * ldo + colb + lane * 8] = ov;
                    } else {
                        s16x4 ov;
#pragma unroll
                        for (int e = 0; e < 4; ++e) ov[e] = (short)f2b(y[e]);
                        *(s16x4*)&o[(size_t)grow * ldo + colb + lane * 4] = ov;
                    }
                }
            }
        }
    } else {
        // IR==1 small GEMMs: direct stores (mode 0 bf16, mode 1 sigmoid f32)
#pragma unroll
        for (int sub = 0; sub < SUBN; ++sub)
#pragma unroll
        for (int j = 0; j < 4; ++j) {
            const int colh = colb + wave * 64 * SUBN + sub * 64 + j * 16 + fc;
            const float bv = bias[colh];
#pragma unroll
            for (int i = 0; i < IR; ++i)
#pragma unroll
            for (int r = 0; r < 4; ++r) {
                const int row = by * BM + i * 16 + quad * 4 + r;
                const float v = acc[i][sub * 4 + j][r] + bv;
                if (mode == 1)
                    ((float*)outv)[(size_t)row * ldo + colh] = 1.0f / (1.0f + expf(-v));
                else
                    ((u16*)outv)[(size_t)row * ldo + colh] = f2b(v);
            }
        }
    }
}

// ---- prep ---------------------------------------------------------------

__device__ __forceinline__ void cvt_quads(const float* __restrict__ src,
                                          u16* __restrict__ dst, int bi, int tid)
{
#pragma unroll
    for (int c = 0; c < 2; ++c) {
        const int q = bi * 512 + tid + 256 * c;
        f32x4 v = *(const f32x4*)(src + (size_t)q * 4);
        s16x4 o;
        o[0] = (short)f2b(v[0]); o[1] = (short)f2b(v[1]);
        o[2] = (short)f2b(v[2]); o[3] = (short)f2b(v[3]);
        *(s16x4*)(dst + (size_t)q * 4) = o;
    }
}

__device__ void transpose_cvt64(const float* __restrict__ src, int C,
                                u16* __restrict__ dst, int R,
                                int tr, int tc, int tid, float* sm)
{
    const int lr = tid >> 4, lc4 = (tid & 15) * 4;
#pragma unroll
    for (int m = 0; m < 4; ++m) {
        const int i = lr + m * 16;
        f32x4 v = *(const f32x4*)&src[(size_t)(tr + i) * C + tc + lc4];
#pragma unroll
        for (int mm = 0; mm < 4; ++mm) sm[i * 65 + lc4 + mm] = v[mm];
    }
    __syncthreads();
#pragma unroll
    for (int m = 0; m < 4; ++m) {
        const int j = lr + m * 16;
        s16x4 o;
#pragma unroll
        for (int mm = 0; mm < 4; ++mm)
            o[mm] = (short)f2b(sm[(size_t)(lc4 + mm) * 65 + j]);
        *(s16x4*)&dst[(size_t)(tc + j) * R + tr + lc4] = o;
    }
}

__device__ void matvec_rows(const float* __restrict__ M, const float* __restrict__ v,
                            const float* __restrict__ add1, const float* __restrict__ add2,
                            float* __restrict__ out, int r0, int tid, float* sm)
{
    for (int i = tid; i < 512; i += 256) sm[i] = v[i];
    __syncthreads();
    const int row = r0 + (tid & 63), q = tid >> 6;
    float s = 0.f;
    for (int k = q * 128; k < q * 128 + 128; k += 4) {
        f32x4 m = *(const f32x4*)&M[(size_t)row * 512 + k];
        s += m[0] * sm[k] + m[1] * sm[k + 1] + m[2] * sm[k + 2] + m[3] * sm[k + 3];
    }
    sm[512 + tid] = s;
    __syncthreads();
    if (tid < 64)
        out[r0 + tid] = sm[512 + tid] + sm[512 + tid + 64] + sm[512 + tid + 128] +
                        sm[512 + tid + 192] + add1[r0 + tid] + add2[r0 + tid];
}

__global__ __launch_bounds__(256)
void prep_cvt(const float* __restrict__ text, const float* __restrict__ num,
              const float* __restrict__ tp_w, const float* __restrict__ np_w,
              const float* __restrict__ g_w, const float* __restrict__ m1_w,
              const float* __restrict__ m2_w,
              const float* __restrict__ a1_wv, const float* __restrict__ a2_wv,
              const float* __restrict__ a1_wo, const float* __restrict__ a2_wo,
              const float* __restrict__ a1_bv, const float* __restrict__ a1_bo,
              const float* __restrict__ a2_bv, const float* __restrict__ a2_bo,
              const float* __restrict__ tp_b, const float* __restrict__ np_b,
              u16* __restrict__ EMBc, u16* __restrict__ Wbig,
              u16* __restrict__ g_bf, u16* __restrict__ m1_bf, u16* __restrict__ m2_bf,
              u16* __restrict__ a1_wvT, u16* __restrict__ a2_wvT,
              u16* __restrict__ tp_wT, u16* __restrict__ np_wT,
              u16* __restrict__ a1_wo_bf, u16* __restrict__ a2_wo_bf,
              float* __restrict__ w1, float* __restrict__ w2,
              float* __restrict__ zb)
{
    __shared__ float smem[64 * 65];
    const int b = blockIdx.x, tid = threadIdx.x;
    if (b < 4096) {
#pragma unroll
        for (int c = 0; c < 2; ++c) {
            const int q = b * 512 + tid + 256 * c;
            const int e = q * 4, row = e >> 9, col = e & 511;
            const float* src = (col < 256) ? text + (size_t)row * 256 + col
                                           : num + (size_t)row * 256 + (col - 256);
            f32x4 v = *(const f32x4*)src;
            s16x4 o;
            o[0] = (short)f2b(v[0]); o[1] = (short)f2b(v[1]);
            o[2] = (short)f2b(v[2]); o[3] = (short)f2b(v[3]);
            *(s16x4*)(EMBc + e) = o;
        }
    } else if (b < 4352) { cvt_quads(g_w, g_bf, b - 4096, tid); }
    else if (b < 4608) { cvt_quads(m1_w, m1_bf, b - 4352, tid); }
    else if (b < 4672) { cvt_quads(m2_w, m2_bf, b - 4608, tid); }
    else if (b < 4736) {
#pragma unroll
        for (int c = 0; c < 2; ++c) {
            const int q = (b - 4672) * 512 + tid + 256 * c;
            const int e = q * 4, row = e >> 8, col = e & 255;
            f32x4 v = *(const f32x4*)(np_w + e);
            s16x4 o;
            o[0] = (short)f2b(v[0]); o[1] = (short)f2b(v[1]);
            o[2] = (short)f2b(v[2]); o[3] = (short)f2b(v[3]);
            *(s16x4*)(Wbig + (size_t)row * 512 + 256 + col) = o;
        }
    } else if (b < 4800) {
#pragma unroll
        for (int c = 0; c < 2; ++c) {
            const int q = (b - 4736) * 512 + tid + 256 * c;
            const int e = q * 4, row = e >> 8, col = e & 255;
            f32x4 v = *(const f32x4*)(tp_w + e);
            s16x4 o;
            o[0] = (short)f2b(v[0]); o[1] = (short)f2b(v[1]);
            o[2] = (short)f2b(v[2]); o[3] = (short)f2b(v[3]);
            *(s16x4*)(Wbig + (size_t)(512 + row) * 512 + col) = o;
        }
    } else if (b < 4864) {
        const int t = b - 4800;
        transpose_cvt64(a1_wv, 512, a1_wvT, 512, (t >> 3) * 64, (t & 7) * 64, tid, smem);
    } else if (b < 4928) {
        const int t = b - 4864;
        transpose_cvt64(a2_wv, 512, a2_wvT, 512, (t >> 3) * 64, (t & 7) * 64, tid, smem);
    } else if (b < 4960) {
        const int t = b - 4928;
        transpose_cvt64(tp_w, 256, tp_wT, 512, (t >> 2) * 64, (t & 3) * 64, tid, smem);
    } else if (b < 4992) {
        const int t = b - 4960;
        transpose_cvt64(np_w, 256, np_wT, 512, (t >> 2) * 64, (t & 3) * 64, tid, smem);
    } else if (b < 5120) { cvt_quads(a1_wo, a1_wo_bf, b - 4992, tid); }
    else if (b < 5248) { cvt_quads(a2_wo, a2_wo_bf, b - 5120, tid); }
    else if (b < 5256) {
        matvec_rows(a1_wo, a1_bv, a1_bo, np_b, w1, (b - 5248) * 64, tid, smem);
    } else if (b < 5264) {
        matvec_rows(a2_wo, a2_bv, a2_bo, tp_b, w2, (b - 5256) * 64, tid, smem);
    } else {
        *(f32x4*)&zb[tid * 4] = f32x4{0.f, 0.f, 0.f, 0.f};
    }
}

__global__ __launch_bounds__(256)
void prep_bias(const u16* __restrict__ M1, const u16* __restrict__ M2,
               const float* __restrict__ tp_b, const float* __restrict__ np_b,
               const float* __restrict__ w1, const float* __restrict__ w2,
               float* __restrict__ bbig)
{
    __shared__ float sm[768];
    const int b = blockIdx.x, tid = threadIdx.x;
    const int side = b >> 3, r0 = (b & 7) * 64;
    const u16* M = side ? M2 : M1;
    const float* v = side ? np_b : tp_b;
    const float* w = side ? w2 : w1;
    float* out = bbig + side * 512;
    for (int i = tid; i < 512; i += 256) sm[i] = v[i];
    __syncthreads();
    const int row = r0 + (tid & 63), q = tid >> 6;
    float s = 0.f;
    for (int k = q * 128; k < q * 128 + 128; k += 8) {
        s16x8 m = *(const s16x8*)&M[(size_t)row * 512 + k];
#pragma unroll
        for (int j = 0; j < 8; ++j) s += b2f((u16)m[j]) * sm[k + j];
    }
    sm[512 + tid] = s;
    __syncthreads();
    if (tid < 64)
        out[r0 + tid] = sm[512 + tid] + sm[512 + tid + 64] + sm[512 + tid + 128] +
                        sm[512 + tid + 192] + w[r0 + tid];
}

extern "C" void kernel_launch(void* const* d_in, const int* in_sizes, int n_in,
                              void* d_out, int out_size, void* d_ws, size_t ws_size,
                              hipStream_t stream)
{
    const float* text  = (const float*)d_in[0];
    const float* num   = (const float*)d_in[1];
    const float* tp_w  = (const float*)d_in[2];
    const float* tp_b  = (const float*)d_in[3];
    const float* np_w  = (const float*)d_in[4];
    const float* np_b  = (const float*)d_in[5];
    const float* a1_wv = (const float*)d_in[8];
    const float* a1_bv = (const float*)d_in[11];
    const float* a1_wo = (const float*)d_in[12];
    const float* a1_bo = (const float*)d_in[13];
    const float* a2_wv = (const float*)d_in[16];
    const float* a2_bv = (const float*)d_in[19];
    const float* a2_wo = (const float*)d_in[20];
    const float* a2_bo = (const float*)d_in[21];
    const float* n1_g  = (const float*)d_in[22];
    const float* n1_b  = (const float*)d_in[23];
    const float* n2_g  = (const float*)d_in[24];
    const float* n2_b  = (const float*)d_in[25];
    const float* g_w   = (const float*)d_in[26];
    const float* g_b   = (const float*)d_in[27];
    const float* m1_w  = (const float*)d_in[28];
    const float* m1_b  = (const float*)d_in[29];
    const float* ln1_g = (const float*)d_in[30];
    const float* ln1_b = (const float*)d_in[31];
    const float* m2_w  = (const float*)d_in[32];
    const float* m2_b  = (const float*)d_in[33];
    const float* ln2_g = (const float*)d_in[34];
    const float* ln2_b = (const float*)d_in[35];

    float* outp = (float*)d_out;
    char* ob = (char*)d_out;
    char* ws = (char*)d_ws;
    const size_t KB = 1024, MB = 1048576;

    // d_out scratch: [0,16MB) dead until G3; [16,48MB) dead until G2 (EMBc)
    u16* Wbig    = (u16*)(ob);                       // 1 MB   [1024x512]
    u16* g_bf    = (u16*)(ob + 1 * MB);              // 1 MB   [512x1024]
    u16* m1_bf   = (u16*)(ob + 2 * MB);              // 1 MB   [512x1024]
    u16* a1_wvT  = (u16*)(ob + 3 * MB + 256 * KB);   // 512 KB [512x512]
    u16* a2_wvT  = (u16*)(ob + 3 * MB + 768 * KB);   // 512 KB
    u16* tp_wT   = (u16*)(ob + 4 * MB + 256 * KB);   // 256 KB [256x512]
    u16* np_wT   = (u16*)(ob + 4 * MB + 512 * KB);   // 256 KB
    u16* a1_wo_bf= (u16*)(ob + 4 * MB + 768 * KB);   // 512 KB [512x512]
    u16* a2_wo_bf= (u16*)(ob + 5 * MB + 256 * KB);   // 512 KB
    u16* M1      = (u16*)(ob + 5 * MB + 768 * KB);   // 512 KB [512x512]
    u16* M2      = (u16*)(ob + 6 * MB + 256 * KB);   // 512 KB
    float* w1    = (float*)(ob + 6 * MB + 768 * KB); // 2 KB
    float* w2    = w1 + 512;                         // 2 KB
    float* bbig  = w1 + 1024;                        // 4 KB
    float* zb    = w1 + 2048;                        // 4 KB
    u16* EMBc    = (u16*)(ob + 16 * MB);             // 16 MB [16384x512]
    // ws: X live prep->G2; m2_bf live prep->G3; h live G2->G3.
    u16* X     = (u16*)ws;                           // 32 MB [16384x1024]
    u16* m2_bf = (u16*)(ws + 32 * MB);               // 256 KB [256x512]
    u16* h     = (u16*)(ws + 48 * MB);               // 16 MB [16384x512]

    dim3 blk(256);

    // P1: conversions, transposes, w1/w2, zbias
    prep_cvt<<<5265, blk, 0, stream>>>(text, num, tp_w, np_w, g_w, m1_w, m2_w,
        a1_wv, a2_wv, a1_wo, a2_wo, a1_bv, a1_bo, a2_bv, a2_bo, tp_b, np_b,
        EMBc, Wbig, g_bf, m1_bf, m2_bf, a1_wvT, a2_wvT, tp_wT, np_wT,
        a1_wo_bf, a2_wo_bf, w1, w2, zb);
    // F1: M1 = a1_wo@a1_wv ; M2 = a2_wo@a2_wv   (16-row tiles -> 128 blocks)
    gemm_bt<1, 1><<<dim3(4, 32), blk, 0, stream>>>(a1_wo_bf, a2_wo_bf, a1_wvT, a2_wvT,
        zb, zb, nullptr, nullptr, nullptr, nullptr,
        M1, M2, 512, 512, 2, 512, 512, 0, 0);
    // PB: bbig = [M1@tp_b + w1 | M2@np_b + w2]
    prep_bias<<<16, blk, 0, stream>>>(M1, M2, tp_b, np_b, w1, w2, bbig);
    // F2: Wbig[0:512,0:256] = M1@tp_w ; Wbig[512:,256:] = M2@np_w (64 blocks)
    gemm_bt<1, 1><<<dim3(2, 32), blk, 0, stream>>>(M1, M2, tp_wT, np_wT,
        zb, zb, nullptr, nullptr, nullptr, nullptr,
        Wbig, Wbig + (size_t)512 * 512 + 256, 512, 512, 1, 512, 512, 0, 0);
    // G1+L1: X = LN(EMBc @ Wbig.T + bbig) per 512-col half (n1 | n2), fused
    gemm_bt<2, 4><<<dim3(2, 256), blk, 0, stream>>>(EMBc, EMBc,
        Wbig, Wbig + (size_t)512 * 512, bbig, bbig + 512,
        n1_g, n1_b, n2_g, n2_b,
        X, X + 512, 512, 512, 1, 1024, 1024, 2, 2);
    // G2+L2: gate = sigmoid(comb@g_w.T+g_b) -> d_out f32 (coalesced) ; h = gelu(LN1(...))
    gemm_bt<2, 4><<<dim3(2, 256), blk, 0, stream>>>(X, X, g_bf, m1_bf, g_b, m1_b,
        nullptr, nullptr, ln1_g, ln1_b,
        outp + (size_t)16384 * 256, h, 1024, 1024, 1, 512, 512, 1, 3);
    // G3+L3: fused = gelu(LN2(h @ m2_w.T + m2_b)) -> d_out f32; attn = 1.0
    gemm_bt<1, 4><<<dim3(1, 256), blk, 0, stream>>>(h, h, m2_bf, m2_bf, m2_b, m2_b,
        ln2_g, ln2_b, ln2_g, ln2_b,
        outp, outp, 512, 512, 1, 256, 256, 4, 4);
}

// Round 13
// 284.311 us; speedup vs baseline: 1.2487x; 1.0326x over previous
//
#include <hip/hip_runtime.h>
#include <math.h>

typedef unsigned short u16;
typedef __bf16 bf16x8 __attribute__((ext_vector_type(8)));
typedef float f32x4 __attribute__((ext_vector_type(4)));
typedef short s16x8 __attribute__((ext_vector_type(8)));
typedef short s16x4 __attribute__((ext_vector_type(4)));

__device__ __forceinline__ float b2f(u16 u) {
    union { unsigned i; float f; } c; c.i = ((unsigned)u) << 16; return c.f;
}
__device__ __forceinline__ u16 f2b(float f) {
    union { float f; unsigned i; } c; c.f = f;
    return (u16)((c.i + 0x7fffu + ((c.i >> 16) & 1u)) >> 16);
}
__device__ __forceinline__ float gelu_f(float v) {
    return 0.5f * v * (1.0f + erff(v * 0.70710678118654752f));
}
__device__ __forceinline__ void async_cp16(const u16* g, u16* l) {
    __builtin_amdgcn_global_load_lds((const __attribute__((address_space(1))) void*)g,
                                     (__attribute__((address_space(3))) void*)l, 16, 0, 0);
}

// C[m][colh] = sum_k A[m][k]*W[colh][k] + bias[colh]; A/W bf16, bias f32.
// Block = (IR*16) rows x (256*SUBN) cols; 4 waves side-by-side in cols.
// K-loop: BK=64, single-buffered, plain __syncthreads. This structure is the
// measured optimum across 8 structural variants (dbuf-drain, counted-vmcnt,
// TLP-tiles, 1-block/CU big-tile, 4-phase pipeline, reg-W all regressed).
// mode 0: bf16 store. mode 1: f32 sigmoid (IR==4/SUBN==2: coalesced via LDS).
// mode 2: LN -> bf16. mode 3: gelu(LN) -> bf16. mode 4: gelu(LN) -> f32 + attn ones.
// LN modes require halfBlocks==1 (block spans the whole LN group) and IR>=2.
// IR=2 exists so G3 (16384 rows / 32 = 512 blocks) gets 2 blocks/CU overlap.
template<int SUBN, int IR>
__global__ __launch_bounds__(256, 2)
void gemm_bt(const u16* __restrict__ A0, const u16* __restrict__ A1,
             const u16* __restrict__ W0, const u16* __restrict__ W1,
             const float* __restrict__ B0, const float* __restrict__ B1,
             const float* __restrict__ LG0, const float* __restrict__ LB0,
             const float* __restrict__ LG1, const float* __restrict__ LB1,
             void* __restrict__ O0v, void* __restrict__ O1v,
             int lda, int K, int halfBlocks, int ldo0, int ldo1,
             int mode0, int mode1)
{
    constexpr int BM   = IR * 16;
    constexpr int NCOL = 256 * SUBN;
    constexpr int WCH  = 8 * SUBN;
    constexpr int EPIW = NCOL + 8;
    constexpr int STAGEU = (BM + NCOL) * 64;
    constexpr int EPIS = (IR >= 2) ? BM * EPIW : 0;
    __shared__ u16 sm[(STAGEU > EPIS) ? STAGEU : EPIS];
    u16* sA = sm;
    u16* sW = sm + BM * 64;

    const int bx = blockIdx.x, by = blockIdx.y;
    const int half = (bx >= halfBlocks) ? 1 : 0;
    const int bxl = bx - half * halfBlocks;
    const u16* A = (half ? A1 : A0) + (size_t)by * BM * lda;
    const u16* W = (half ? W1 : W0) + (size_t)bxl * NCOL * K;
    const float* bias = half ? B1 : B0;
    const float* lng = half ? LG1 : LG0;
    const float* lnb = half ? LB1 : LB0;
    void* outv = half ? O1v : O0v;
    const int ldo = half ? ldo1 : ldo0;
    const int mode = half ? mode1 : mode0;

    const int tid = threadIdx.x;
    const int lane = tid & 63;
    const int wave = tid >> 6;
    const int fc = lane & 15;
    const int quad = lane >> 4;

    // chunk slot p (16B) holds row r=p>>3, logical k8-chunk c8=((p&7)-(r&7))&7;
    // physical slot for (r,c8) is r*8 + ((c8 + r)&7) -> bank-spread frag reads.
    int par[2], pac[2];
#pragma unroll
    for (int c = 0; c < 2; ++c) {
        const int p = tid + 256 * c;
        par[c] = p >> 3;
        pac[c] = ((p & 7) - (par[c] & 7)) & 7;
    }
    int pwr[WCH], pwc[WCH];
#pragma unroll
    for (int c = 0; c < WCH; ++c) {
        const int p = tid + 256 * c;
        pwr[c] = p >> 3;
        pwc[c] = ((p & 7) - (pwr[c] & 7)) & 7;
    }

    f32x4 acc[IR][4 * SUBN];
#pragma unroll
    for (int i = 0; i < IR; ++i)
#pragma unroll
        for (int j = 0; j < 4 * SUBN; ++j)
            acc[i][j] = f32x4{0.f, 0.f, 0.f, 0.f};

    for (int k0 = 0; k0 < K; k0 += 64) {
#pragma unroll
        for (int c = 0; c < 2; ++c) {
            const int p = tid + 256 * c;
            if (p < BM * 8)
                async_cp16(A + (size_t)par[c] * lda + k0 + pac[c] * 8, &sA[p * 8]);
        }
#pragma unroll
        for (int c = 0; c < WCH; ++c)
            async_cp16(W + (size_t)pwr[c] * K + k0 + pwc[c] * 8,
                       &sW[(tid + 256 * c) * 8]);
        __syncthreads();

#pragma unroll
        for (int kk = 0; kk < 2; ++kk) {
            bf16x8 af[IR];
#pragma unroll
            for (int i = 0; i < IR; ++i) {
                const int ar = i * 16 + fc;
                const int slot = ar * 8 + ((kk * 4 + quad + (ar & 7)) & 7);
                af[i] = *(const bf16x8*)&sA[slot * 8];
            }
#pragma unroll
            for (int sub = 0; sub < SUBN; ++sub) {
                bf16x8 wf[4];
#pragma unroll
                for (int j = 0; j < 4; ++j) {
                    const int wr = wave * 64 * SUBN + sub * 64 + j * 16 + fc;
                    const int slot = wr * 8 + ((kk * 4 + quad + (wr & 7)) & 7);
                    wf[j] = *(const bf16x8*)&sW[slot * 8];
                }
#pragma unroll
                for (int i = 0; i < IR; ++i)
#pragma unroll
                    for (int j = 0; j < 4; ++j)
                        acc[i][sub * 4 + j] =
                            __builtin_amdgcn_mfma_f32_16x16x32_bf16(af[i], wf[j], acc[i][sub * 4 + j], 0, 0, 0);
            }
        }
        __syncthreads();
    }

    const int colb = bxl * NCOL;

    if constexpr (IR >= 2) {
        if (mode == 1) {
            if constexpr (SUBN == 2 && IR == 4) {
                // gate: sigmoid f32, coalesced via LDS (byte-identical to the
                // twice-passing R9/R12 path; stride 528, known 262K conflicts,
                // ~0.5us, accepted pending infra-ambiguity resolution).
                // 2 passes of 32 rows; sf = 32 x 528 f32 = 67.5 KB <= 72 KB.
                float* sf = (float*)sm;
                float bb2[8];
#pragma unroll
                for (int sub = 0; sub < 2; ++sub)
#pragma unroll
                for (int j = 0; j < 4; ++j)
                    bb2[sub * 4 + j] = bias[colb + wave * 128 + sub * 64 + j * 16 + fc];
#pragma unroll
                for (int p = 0; p < 2; ++p) {
#pragma unroll
                    for (int i2 = 0; i2 < 2; ++i2) {
                        const int i = 2 * p + i2;
#pragma unroll
                        for (int sub = 0; sub < 2; ++sub)
#pragma unroll
                        for (int j = 0; j < 4; ++j) {
                            const int col = wave * 128 + sub * 64 + j * 16 + fc;
#pragma unroll
                            for (int r = 0; r < 4; ++r)
                                sf[(i2 * 16 + quad * 4 + r) * 528 + col] =
                                    1.0f / (1.0f + expf(-(acc[i][sub * 4 + j][r] + bb2[sub * 4 + j])));
                        }
                    }
                    __syncthreads();
                    // 32 rows x 512 f32, consecutive-lane f32x4 (4KB/instr, coalesced)
                    float* o = (float*)outv;
#pragma unroll
                    for (int it = 0; it < 16; ++it) {
                        const int idx = it * 1024 + tid * 4;   // f32 units
                        const int row = idx >> 9, col = idx & 511;
                        const int grow = by * 64 + p * 32 + row;
                        *(f32x4*)&o[(size_t)grow * ldo + colb + col] =
                            *(const f32x4*)&sf[row * 528 + col];
                    }
                    __syncthreads();
                }
            }
        } else if (mode == 0) {
            // direct bf16 store
#pragma unroll
            for (int sub = 0; sub < SUBN; ++sub)
#pragma unroll
            for (int j = 0; j < 4; ++j) {
                const int colh = colb + wave * 64 * SUBN + sub * 64 + j * 16 + fc;
                const float bv = bias[colh];
#pragma unroll
                for (int i = 0; i < IR; ++i)
#pragma unroll
                for (int r = 0; r < 4; ++r) {
                    const int row = by * BM + i * 16 + quad * 4 + r;
                    ((u16*)outv)[(size_t)row * ldo + colh] = f2b(acc[i][sub * 4 + j][r] + bv);
                }
            }
        } else {
            // fused LN epilogue (bit-identical numerics; generalized to BM rows)
            float bb[SUBN * 4];
#pragma unroll
            for (int sub = 0; sub < SUBN; ++sub)
#pragma unroll
            for (int j = 0; j < 4; ++j)
                bb[sub * 4 + j] = bias[colb + wave * 64 * SUBN + sub * 64 + j * 16 + fc];
#pragma unroll
            for (int sub = 0; sub < SUBN; ++sub)
#pragma unroll
            for (int j = 0; j < 4; ++j) {
                const int col = wave * 64 * SUBN + sub * 64 + j * 16 + fc;
#pragma unroll
                for (int i = 0; i < IR; ++i)
#pragma unroll
                for (int r = 0; r < 4; ++r)
                    sm[(i * 16 + quad * 4 + r) * EPIW + col] =
                        f2b(acc[i][sub * 4 + j][r] + bb[sub * 4 + j]);
            }
            __syncthreads();

            constexpr int CE = NCOL / 64;
            constexpr int RPW = BM / 4;        // rows per wave in LN phase
            constexpr float INV = 1.0f / (float)NCOL;
            float gv[CE], bvv[CE];
#pragma unroll
            for (int e = 0; e < CE; ++e) {
                gv[e] = lng[lane * CE + e];
                bvv[e] = lnb[lane * CE + e];
            }
            for (int rr = 0; rr < RPW; ++rr) {
                const int rl = wave * RPW + rr;
                const int grow = by * BM + rl;
                float x[CE], s = 0.f, ss = 0.f;
                if constexpr (CE == 8) {
                    s16x8 xv = *(const s16x8*)&sm[rl * EPIW + lane * 8];
#pragma unroll
                    for (int e = 0; e < 8; ++e) { x[e] = b2f((u16)xv[e]); s += x[e]; ss += x[e] * x[e]; }
                } else {
                    s16x4 xv = *(const s16x4*)&sm[rl * EPIW + lane * 4];
#pragma unroll
                    for (int e = 0; e < 4; ++e) { x[e] = b2f((u16)xv[e]); s += x[e]; ss += x[e] * x[e]; }
                }
#pragma unroll
                for (int m = 32; m >= 1; m >>= 1) { s += __shfl_xor(s, m, 64); ss += __shfl_xor(ss, m, 64); }
                const float mean = s * INV;
                const float var = ss * INV - mean * mean;
                const float rs = rsqrtf(var + 1e-5f);
                float y[CE];
#pragma unroll
                for (int e = 0; e < CE; ++e) {
                    y[e] = (x[e] - mean) * rs * gv[e] + bvv[e];
                    if (mode >= 3) y[e] = gelu_f(y[e]);
                }
                if (mode == 4) {
                    float* o = (float*)outv;
                    if constexpr (CE == 4) {
                        f32x4 yv; yv[0] = y[0]; yv[1] = y[1]; yv[2] = y[2]; yv[3] = y[3];
                        *(f32x4*)&o[(size_t)grow * ldo + colb + lane * 4] = yv;
                    } else {
#pragma unroll
                        for (int e = 0; e < CE; ++e)
                            o[(size_t)grow * ldo + colb + lane * CE + e] = y[e];
                    }
                    if (lane == 0) {
                        o[(size_t)16384 * 768 + grow] = 1.0f;
                        o[(size_t)16384 * 769 + grow] = 1.0f;
                    }
                } else {
                    u16* o = (u16*)outv;
                    if constexpr (CE == 8) {
                        s16x8 ov;
#pragma unroll
                        for (int e = 0; e < 8; ++e) ov[e] = (short)f2b(y[e]);
                        *(s16x8*)&o[(size_t)grow * ldo + colb + lane * 8] = ov;
                    } else {
                        s16x4 ov;
#pragma unroll
                        for (int e = 0; e < 4; ++e) ov[e] = (short)f2b(y[e]);
                        *(s16x4*)&o[(size_t)grow * ldo + colb + lane * 4] = ov;
                    }
                }
            }
        }
    } else {
        // IR==1 small GEMMs: direct stores (mode 0 bf16, mode 1 sigmoid f32)
#pragma unroll
        for (int sub = 0; sub < SUBN; ++sub)
#pragma unroll
        for (int j = 0; j < 4; ++j) {
            const int colh = colb + wave * 64 * SUBN + sub * 64 + j * 16 + fc;
            const float bv = bias[colh];
#pragma unroll
            for (int i = 0; i < IR; ++i)
#pragma unroll
            for (int r = 0; r < 4; ++r) {
                const int row = by * BM + i * 16 + quad * 4 + r;
                const float v = acc[i][sub * 4 + j][r] + bv;
                if (mode == 1)
                    ((float*)outv)[(size_t)row * ldo + colh] = 1.0f / (1.0f + expf(-v));
                else
                    ((u16*)outv)[(size_t)row * ldo + colh] = f2b(v);
            }
        }
    }
}

// ---- prep ---------------------------------------------------------------

__device__ __forceinline__ void cvt_quads(const float* __restrict__ src,
                                          u16* __restrict__ dst, int bi, int tid)
{
#pragma unroll
    for (int c = 0; c < 2; ++c) {
        const int q = bi * 512 + tid + 256 * c;
        f32x4 v = *(const f32x4*)(src + (size_t)q * 4);
        s16x4 o;
        o[0] = (short)f2b(v[0]); o[1] = (short)f2b(v[1]);
        o[2] = (short)f2b(v[2]); o[3] = (short)f2b(v[3]);
        *(s16x4*)(dst + (size_t)q * 4) = o;
    }
}

__device__ void transpose_cvt64(const float* __restrict__ src, int C,
                                u16* __restrict__ dst, int R,
                                int tr, int tc, int tid, float* sm)
{
    const int lr = tid >> 4, lc4 = (tid & 15) * 4;
#pragma unroll
    for (int m = 0; m < 4; ++m) {
        const int i = lr + m * 16;
        f32x4 v = *(const f32x4*)&src[(size_t)(tr + i) * C + tc + lc4];
#pragma unroll
        for (int mm = 0; mm < 4; ++mm) sm[i * 65 + lc4 + mm] = v[mm];
    }
    __syncthreads();
#pragma unroll
    for (int m = 0; m < 4; ++m) {
        const int j = lr + m * 16;
        s16x4 o;
#pragma unroll
        for (int mm = 0; mm < 4; ++mm)
            o[mm] = (short)f2b(sm[(size_t)(lc4 + mm) * 65 + j]);
        *(s16x4*)&dst[(size_t)(tc + j) * R + tr + lc4] = o;
    }
}

__device__ void matvec_rows(const float* __restrict__ M, const float* __restrict__ v,
                            const float* __restrict__ add1, const float* __restrict__ add2,
                            float* __restrict__ out, int r0, int tid, float* sm)
{
    for (int i = tid; i < 512; i += 256) sm[i] = v[i];
    __syncthreads();
    const int row = r0 + (tid & 63), q = tid >> 6;
    float s = 0.f;
    for (int k = q * 128; k < q * 128 + 128; k += 4) {
        f32x4 m = *(const f32x4*)&M[(size_t)row * 512 + k];
        s += m[0] * sm[k] + m[1] * sm[k + 1] + m[2] * sm[k + 2] + m[3] * sm[k + 3];
    }
    sm[512 + tid] = s;
    __syncthreads();
    if (tid < 64)
        out[r0 + tid] = sm[512 + tid] + sm[512 + tid + 64] + sm[512 + tid + 128] +
                        sm[512 + tid + 192] + add1[r0 + tid] + add2[r0 + tid];
}

__global__ __launch_bounds__(256)
void prep_cvt(const float* __restrict__ text, const float* __restrict__ num,
              const float* __restrict__ tp_w, const float* __restrict__ np_w,
              const float* __restrict__ g_w, const float* __restrict__ m1_w,
              const float* __restrict__ m2_w,
              const float* __restrict__ a1_wv, const float* __restrict__ a2_wv,
              const float* __restrict__ a1_wo, const float* __restrict__ a2_wo,
              const float* __restrict__ a1_bv, const float* __restrict__ a1_bo,
              const float* __restrict__ a2_bv, const float* __restrict__ a2_bo,
              const float* __restrict__ tp_b, const float* __restrict__ np_b,
              u16* __restrict__ EMBc, u16* __restrict__ Wbig,
              u16* __restrict__ g_bf, u16* __restrict__ m1_bf, u16* __restrict__ m2_bf,
              u16* __restrict__ a1_wvT, u16* __restrict__ a2_wvT,
              u16* __restrict__ tp_wT, u16* __restrict__ np_wT,
              u16* __restrict__ a1_wo_bf, u16* __restrict__ a2_wo_bf,
              float* __restrict__ w1, float* __restrict__ w2,
              float* __restrict__ zb)
{
    __shared__ float smem[64 * 65];
    const int b = blockIdx.x, tid = threadIdx.x;
    if (b < 4096) {
#pragma unroll
        for (int c = 0; c < 2; ++c) {
            const int q = b * 512 + tid + 256 * c;
            const int e = q * 4, row = e >> 9, col = e & 511;
            const float* src = (col < 256) ? text + (size_t)row * 256 + col
                                           : num + (size_t)row * 256 + (col - 256);
            f32x4 v = *(const f32x4*)src;
            s16x4 o;
            o[0] = (short)f2b(v[0]); o[1] = (short)f2b(v[1]);
            o[2] = (short)f2b(v[2]); o[3] = (short)f2b(v[3]);
            *(s16x4*)(EMBc + e) = o;
        }
    } else if (b < 4352) { cvt_quads(g_w, g_bf, b - 4096, tid); }
    else if (b < 4608) { cvt_quads(m1_w, m1_bf, b - 4352, tid); }
    else if (b < 4672) { cvt_quads(m2_w, m2_bf, b - 4608, tid); }
    else if (b < 4736) {
#pragma unroll
        for (int c = 0; c < 2; ++c) {
            const int q = (b - 4672) * 512 + tid + 256 * c;
            const int e = q * 4, row = e >> 8, col = e & 255;
            f32x4 v = *(const f32x4*)(np_w + e);
            s16x4 o;
            o[0] = (short)f2b(v[0]); o[1] = (short)f2b(v[1]);
            o[2] = (short)f2b(v[2]); o[3] = (short)f2b(v[3]);
            *(s16x4*)(Wbig + (size_t)row * 512 + 256 + col) = o;
        }
    } else if (b < 4800) {
#pragma unroll
        for (int c = 0; c < 2; ++c) {
            const int q = (b - 4736) * 512 + tid + 256 * c;
            const int e = q * 4, row = e >> 8, col = e & 255;
            f32x4 v = *(const f32x4*)(tp_w + e);
            s16x4 o;
            o[0] = (short)f2b(v[0]); o[1] = (short)f2b(v[1]);
            o[2] = (short)f2b(v[2]); o[3] = (short)f2b(v[3]);
            *(s16x4*)(Wbig + (size_t)(512 + row) * 512 + col) = o;
        }
    } else if (b < 4864) {
        const int t = b - 4800;
        transpose_cvt64(a1_wv, 512, a1_wvT, 512, (t >> 3) * 64, (t & 7) * 64, tid, smem);
    } else if (b < 4928) {
        const int t = b - 4864;
        transpose_cvt64(a2_wv, 512, a2_wvT, 512, (t >> 3) * 64, (t & 7) * 64, tid, smem);
    } else if (b < 4960) {
        const int t = b - 4928;
        transpose_cvt64(tp_w, 256, tp_wT, 512, (t >> 2) * 64, (t & 3) * 64, tid, smem);
    } else if (b < 4992) {
        const int t = b - 4960;
        transpose_cvt64(np_w, 256, np_wT, 512, (t >> 2) * 64, (t & 3) * 64, tid, smem);
    } else if (b < 5120) { cvt_quads(a1_wo, a1_wo_bf, b - 4992, tid); }
    else if (b < 5248) { cvt_quads(a2_wo, a2_wo_bf, b - 5120, tid); }
    else if (b < 5256) {
        matvec_rows(a1_wo, a1_bv, a1_bo, np_b, w1, (b - 5248) * 64, tid, smem);
    } else if (b < 5264) {
        matvec_rows(a2_wo, a2_bv, a2_bo, tp_b, w2, (b - 5256) * 64, tid, smem);
    } else {
        *(f32x4*)&zb[tid * 4] = f32x4{0.f, 0.f, 0.f, 0.f};
    }
}

__global__ __launch_bounds__(256)
void prep_bias(const u16* __restrict__ M1, const u16* __restrict__ M2,
               const float* __restrict__ tp_b, const float* __restrict__ np_b,
               const float* __restrict__ w1, const float* __restrict__ w2,
               float* __restrict__ bbig)
{
    __shared__ float sm[768];
    const int b = blockIdx.x, tid = threadIdx.x;
    const int side = b >> 3, r0 = (b & 7) * 64;
    const u16* M = side ? M2 : M1;
    const float* v = side ? np_b : tp_b;
    const float* w = side ? w2 : w1;
    float* out = bbig + side * 512;
    for (int i = tid; i < 512; i += 256) sm[i] = v[i];
    __syncthreads();
    const int row = r0 + (tid & 63), q = tid >> 6;
    float s = 0.f;
    for (int k = q * 128; k < q * 128 + 128; k += 8) {
        s16x8 m = *(const s16x8*)&M[(size_t)row * 512 + k];
#pragma unroll
        for (int j = 0; j < 8; ++j) s += b2f((u16)m[j]) * sm[k + j];
    }
    sm[512 + tid] = s;
    __syncthreads();
    if (tid < 64)
        out[r0 + tid] = sm[512 + tid] + sm[512 + tid + 64] + sm[512 + tid + 128] +
                        sm[512 + tid + 192] + w[r0 + tid];
}

extern "C" void kernel_launch(void* const* d_in, const int* in_sizes, int n_in,
                              void* d_out, int out_size, void* d_ws, size_t ws_size,
                              hipStream_t stream)
{
    const float* text  = (const float*)d_in[0];
    const float* num   = (const float*)d_in[1];
    const float* tp_w  = (const float*)d_in[2];
    const float* tp_b  = (const float*)d_in[3];
    const float* np_w  = (const float*)d_in[4];
    const float* np_b  = (const float*)d_in[5];
    const float* a1_wv = (const float*)d_in[8];
    const float* a1_bv = (const float*)d_in[11];
    const float* a1_wo = (const float*)d_in[12];
    const float* a1_bo = (const float*)d_in[13];
    const float* a2_wv = (const float*)d_in[16];
    const float* a2_bv = (const float*)d_in[19];
    const float* a2_wo = (const float*)d_in[20];
    const float* a2_bo = (const float*)d_in[21];
    const float* n1_g  = (const float*)d_in[22];
    const float* n1_b  = (const float*)d_in[23];
    const float* n2_g  = (const float*)d_in[24];
    const float* n2_b  = (const float*)d_in[25];
    const float* g_w   = (const float*)d_in[26];
    const float* g_b   = (const float*)d_in[27];
    const float* m1_w  = (const float*)d_in[28];
    const float* m1_b  = (const float*)d_in[29];
    const float* ln1_g = (const float*)d_in[30];
    const float* ln1_b = (const float*)d_in[31];
    const float* m2_w  = (const float*)d_in[32];
    const float* m2_b  = (const float*)d_in[33];
    const float* ln2_g = (const float*)d_in[34];
    const float* ln2_b = (const float*)d_in[35];

    float* outp = (float*)d_out;
    char* ob = (char*)d_out;
    char* ws = (char*)d_ws;
    const size_t KB = 1024, MB = 1048576;

    // d_out scratch: [0,16MB) dead until G3; [16,48MB) dead until G2 (EMBc)
    u16* Wbig    = (u16*)(ob);                       // 1 MB   [1024x512]
    u16* g_bf    = (u16*)(ob + 1 * MB);              // 1 MB   [512x1024]
    u16* m1_bf   = (u16*)(ob + 2 * MB);              // 1 MB   [512x1024]
    u16* a1_wvT  = (u16*)(ob + 3 * MB + 256 * KB);   // 512 KB [512x512]
    u16* a2_wvT  = (u16*)(ob + 3 * MB + 768 * KB);   // 512 KB
    u16* tp_wT   = (u16*)(ob + 4 * MB + 256 * KB);   // 256 KB [256x512]
    u16* np_wT   = (u16*)(ob + 4 * MB + 512 * KB);   // 256 KB
    u16* a1_wo_bf= (u16*)(ob + 4 * MB + 768 * KB);   // 512 KB [512x512]
    u16* a2_wo_bf= (u16*)(ob + 5 * MB + 256 * KB);   // 512 KB
    u16* M1      = (u16*)(ob + 5 * MB + 768 * KB);   // 512 KB [512x512]
    u16* M2      = (u16*)(ob + 6 * MB + 256 * KB);   // 512 KB
    float* w1    = (float*)(ob + 6 * MB + 768 * KB); // 2 KB
    float* w2    = w1 + 512;                         // 2 KB
    float* bbig  = w1 + 1024;                        // 4 KB
    float* zb    = w1 + 2048;                        // 4 KB
    u16* EMBc    = (u16*)(ob + 16 * MB);             // 16 MB [16384x512]
    // ws: X live prep->G2; m2_bf live prep->G3; h live G2->G3.
    u16* X     = (u16*)ws;                           // 32 MB [16384x1024]
    u16* m2_bf = (u16*)(ws + 32 * MB);               // 256 KB [256x512]
    u16* h     = (u16*)(ws + 48 * MB);               // 16 MB [16384x512]

    dim3 blk(256);

    // P1: conversions, transposes, w1/w2, zbias
    prep_cvt<<<5265, blk, 0, stream>>>(text, num, tp_w, np_w, g_w, m1_w, m2_w,
        a1_wv, a2_wv, a1_wo, a2_wo, a1_bv, a1_bo, a2_bv, a2_bo, tp_b, np_b,
        EMBc, Wbig, g_bf, m1_bf, m2_bf, a1_wvT, a2_wvT, tp_wT, np_wT,
        a1_wo_bf, a2_wo_bf, w1, w2, zb);
    // F1: M1 = a1_wo@a1_wv ; M2 = a2_wo@a2_wv   (16-row tiles -> 128 blocks)
    gemm_bt<1, 1><<<dim3(4, 32), blk, 0, stream>>>(a1_wo_bf, a2_wo_bf, a1_wvT, a2_wvT,
        zb, zb, nullptr, nullptr, nullptr, nullptr,
        M1, M2, 512, 512, 2, 512, 512, 0, 0);
    // PB: bbig = [M1@tp_b + w1 | M2@np_b + w2]
    prep_bias<<<16, blk, 0, stream>>>(M1, M2, tp_b, np_b, w1, w2, bbig);
    // F2: Wbig[0:512,0:256] = M1@tp_w ; Wbig[512:,256:] = M2@np_w (64 blocks)
    gemm_bt<1, 1><<<dim3(2, 32), blk, 0, stream>>>(M1, M2, tp_wT, np_wT,
        zb, zb, nullptr, nullptr, nullptr, nullptr,
        Wbig, Wbig + (size_t)512 * 512 + 256, 512, 512, 1, 512, 512, 0, 0);
    // G1+L1: X = LN(EMBc @ Wbig.T + bbig) per 512-col half (n1 | n2), fused
    gemm_bt<2, 4><<<dim3(2, 256), blk, 0, stream>>>(EMBc, EMBc,
        Wbig, Wbig + (size_t)512 * 512, bbig, bbig + 512,
        n1_g, n1_b, n2_g, n2_b,
        X, X + 512, 512, 512, 1, 1024, 1024, 2, 2);
    // G2+L2: gate = sigmoid(comb@g_w.T+g_b) -> d_out f32 (coalesced) ; h = gelu(LN1(...))
    gemm_bt<2, 4><<<dim3(2, 256), blk, 0, stream>>>(X, X, g_bf, m1_bf, g_b, m1_b,
        nullptr, nullptr, ln1_g, ln1_b,
        outp + (size_t)16384 * 256, h, 1024, 1024, 1, 512, 512, 1, 3);
    // G3+L3: fused = gelu(LN2(h @ m2_w.T + m2_b)) -> d_out f32; attn = 1.0
    // IR=2 (32-row blocks) -> 512 blocks = 2 blocks/CU (was 256 = 1/CU, zero overlap)
    gemm_bt<1, 2><<<dim3(1, 512), blk, 0, stream>>>(h, h, m2_bf, m2_bf, m2_b, m2_b,
        ln2_g, ln2_b, ln2_g, ln2_b,
        outp, outp, 512, 512, 1, 256, 256, 4, 4);
}